// Round 1
// baseline (424.229 us; speedup 1.0000x reference)
//
#include <hip/hip_runtime.h>
#include <hip/hip_bf16.h>

// DotProductAttention: N=8, TD=1024, TE=2048, D=1024, fp32 in/out.
// Pipeline: scores GEMM (bf16 MFMA, cast-on-load) -> masked softmax in-place
// in d_out's alignments region -> contexts GEMM.
#define NB 8
#define TDIM 1024
#define TEDIM 2048
#define DDIM 1024

typedef __bf16 bf16x8 __attribute__((ext_vector_type(8)));
typedef float f32x4 __attribute__((ext_vector_type(4)));

static __device__ __forceinline__ ushort4 cvt4_bf16(float4 v) {
    __bf16 a = (__bf16)v.x, b = (__bf16)v.y, c = (__bf16)v.z, d = (__bf16)v.w;
    ushort4 r;
    r.x = __builtin_bit_cast(unsigned short, a);
    r.y = __builtin_bit_cast(unsigned short, b);
    r.z = __builtin_bit_cast(unsigned short, c);
    r.w = __builtin_bit_cast(unsigned short, d);
    return r;
}

// ---------------------------------------------------------------------------
// Kernel 1: S[n][t][s] = dot(Q[n][t][:], M[n][s][:]) / 32
// Both operands K-major (B^T form). 128x128 tile, BK=32, 4 waves.
// ---------------------------------------------------------------------------
__global__ __launch_bounds__(256) void scores_kernel(
    const float* __restrict__ Q, const float* __restrict__ M,
    float* __restrict__ S)
{
    const int n    = blockIdx.z;
    const int row0 = blockIdx.x * 128;   // TD tile
    const int col0 = blockIdx.y * 128;   // TE tile

    const float* Qb = Q + (size_t)n * TDIM * DDIM;
    const float* Mb = M + (size_t)n * TEDIM * DDIM;
    float*       Sb = S + (size_t)n * TDIM * TEDIM;

    __shared__ __bf16 As[128][40];   // pad 40 bf16 = 80 B rows (16B aligned)
    __shared__ __bf16 Bs[128][40];

    const int t    = threadIdx.x;
    const int lane = t & 63;
    const int w    = t >> 6;
    const int wr   = (w >> 1) * 64;  // wave row offset in tile
    const int wc   = (w & 1) * 64;   // wave col offset in tile

    f32x4 acc[4][4] = {};

    for (int k0 = 0; k0 < DDIM; k0 += 32) {
        // stage A (Q tile) and B (M tile), both [128 rows][32 k] fp32->bf16
        #pragma unroll
        for (int j = 0; j < 4; ++j) {
            const int f = j * 256 + t;         // float4 index in tile
            const int r = f >> 3;              // 8 float4 per row of 32
            const int c = (f & 7) * 4;
            float4 va = *reinterpret_cast<const float4*>(
                &Qb[(size_t)(row0 + r) * DDIM + k0 + c]);
            *reinterpret_cast<ushort4*>(&As[r][c]) = cvt4_bf16(va);
            float4 vb = *reinterpret_cast<const float4*>(
                &Mb[(size_t)(col0 + r) * DDIM + k0 + c]);
            *reinterpret_cast<ushort4*>(&Bs[r][c]) = cvt4_bf16(vb);
        }
        __syncthreads();

        bf16x8 af[4], bfr[4];
        #pragma unroll
        for (int i = 0; i < 4; ++i)
            af[i] = *reinterpret_cast<const bf16x8*>(
                &As[wr + i * 16 + (lane & 15)][(lane >> 4) * 8]);
        #pragma unroll
        for (int j = 0; j < 4; ++j)
            bfr[j] = *reinterpret_cast<const bf16x8*>(
                &Bs[wc + j * 16 + (lane & 15)][(lane >> 4) * 8]);

        #pragma unroll
        for (int i = 0; i < 4; ++i)
            #pragma unroll
            for (int j = 0; j < 4; ++j)
                acc[i][j] = __builtin_amdgcn_mfma_f32_16x16x32_bf16(
                    af[i], bfr[j], acc[i][j], 0, 0, 0);
        __syncthreads();
    }

    // epilogue: scale by 1/sqrt(D)=1/32, store raw scores
    const float inv = 0.03125f;
    #pragma unroll
    for (int i = 0; i < 4; ++i) {
        #pragma unroll
        for (int j = 0; j < 4; ++j) {
            const int col   = col0 + wc + j * 16 + (lane & 15);
            const int rbase = row0 + wr + i * 16 + (lane >> 4) * 4;
            #pragma unroll
            for (int r = 0; r < 4; ++r)
                Sb[(size_t)(rbase + r) * TEDIM + col] = acc[i][j][r] * inv;
        }
    }
}

// ---------------------------------------------------------------------------
// Kernel 2: masked softmax over each row of S (length TE), in place.
// One 256-thread block per row; 8 elements/thread, float4 loads.
// ---------------------------------------------------------------------------
__global__ __launch_bounds__(256) void softmax_kernel(
    float* __restrict__ S, const int* __restrict__ len_p)
{
    const int row = blockIdx.x;          // n*TD + t
    const int n   = row >> 10;           // TD = 1024
    const int len = len_p[n];
    float* Sr = S + (size_t)row * TEDIM;

    const int t    = threadIdx.x;
    const int lane = t & 63;
    const int w    = t >> 6;
    const int s0   = t * 8;

    float4 a = *reinterpret_cast<const float4*>(&Sr[s0]);
    float4 b = *reinterpret_cast<const float4*>(&Sr[s0 + 4]);
    float v[8] = {a.x, a.y, a.z, a.w, b.x, b.y, b.z, b.w};
    #pragma unroll
    for (int i = 0; i < 8; ++i)
        if (s0 + i >= len) v[i] = -INFINITY;

    float mx = v[0];
    #pragma unroll
    for (int i = 1; i < 8; ++i) mx = fmaxf(mx, v[i]);
    #pragma unroll
    for (int off = 32; off; off >>= 1) mx = fmaxf(mx, __shfl_xor(mx, off));

    __shared__ float redm[4], reds[4];
    if (lane == 0) redm[w] = mx;
    __syncthreads();
    mx = fmaxf(fmaxf(redm[0], redm[1]), fmaxf(redm[2], redm[3]));

    float e[8];
    float sum = 0.f;
    #pragma unroll
    for (int i = 0; i < 8; ++i) { e[i] = __expf(v[i] - mx); sum += e[i]; }
    #pragma unroll
    for (int off = 32; off; off >>= 1) sum += __shfl_xor(sum, off);
    if (lane == 0) reds[w] = sum;
    __syncthreads();
    sum = reds[0] + reds[1] + reds[2] + reds[3];

    const float r = 1.0f / sum;
    float4 oa = {e[0] * r, e[1] * r, e[2] * r, e[3] * r};
    float4 ob = {e[4] * r, e[5] * r, e[6] * r, e[7] * r};
    *reinterpret_cast<float4*>(&Sr[s0])     = oa;
    *reinterpret_cast<float4*>(&Sr[s0 + 4]) = ob;
}

// ---------------------------------------------------------------------------
// Kernel 3: C[n][t][d] = sum_s A[n][t][s] * M[n][s][d]
// A is K-major; M needs transpose during staging (k strided, n contiguous).
// ---------------------------------------------------------------------------
__global__ __launch_bounds__(256) void contexts_kernel(
    const float* __restrict__ A, const float* __restrict__ M,
    float* __restrict__ C)
{
    const int n    = blockIdx.z;
    const int row0 = blockIdx.x * 128;   // TD tile
    const int col0 = blockIdx.y * 128;   // D tile

    const float* Ab = A + (size_t)n * TDIM * TEDIM;
    const float* Mb = M + (size_t)n * TEDIM * DDIM;
    float*       Cb = C + (size_t)n * TDIM * DDIM;

    __shared__ __bf16 As[128][40];
    __shared__ __bf16 Bs[128][40];

    const int t    = threadIdx.x;
    const int lane = t & 63;
    const int w    = t >> 6;
    const int wr   = (w >> 1) * 64;
    const int wc   = (w & 1) * 64;

    f32x4 acc[4][4] = {};

    for (int k0 = 0; k0 < TEDIM; k0 += 32) {
        // stage A tile [128][32] (K-major, lda=TE)
        #pragma unroll
        for (int j = 0; j < 4; ++j) {
            const int f = j * 256 + t;
            const int r = f >> 3;
            const int c = (f & 7) * 4;
            float4 va = *reinterpret_cast<const float4*>(
                &Ab[(size_t)(row0 + r) * TEDIM + k0 + c]);
            *reinterpret_cast<ushort4*>(&As[r][c]) = cvt4_bf16(va);
        }
        // stage B tile transposed: Bs[d][s] <- M[k0+s][col0+d]
        #pragma unroll
        for (int j = 0; j < 4; ++j) {
            const int f  = j * 256 + t;
            const int k  = f >> 5;            // 32 float4 per k-row (128 d / 4)
            const int nn = (f & 31) * 4;
            float4 vb = *reinterpret_cast<const float4*>(
                &Mb[(size_t)(k0 + k) * DDIM + col0 + nn]);
            Bs[nn + 0][k] = (__bf16)vb.x;
            Bs[nn + 1][k] = (__bf16)vb.y;
            Bs[nn + 2][k] = (__bf16)vb.z;
            Bs[nn + 3][k] = (__bf16)vb.w;
        }
        __syncthreads();

        bf16x8 af[4], bfr[4];
        #pragma unroll
        for (int i = 0; i < 4; ++i)
            af[i] = *reinterpret_cast<const bf16x8*>(
                &As[wr + i * 16 + (lane & 15)][(lane >> 4) * 8]);
        #pragma unroll
        for (int j = 0; j < 4; ++j)
            bfr[j] = *reinterpret_cast<const bf16x8*>(
                &Bs[wc + j * 16 + (lane & 15)][(lane >> 4) * 8]);

        #pragma unroll
        for (int i = 0; i < 4; ++i)
            #pragma unroll
            for (int j = 0; j < 4; ++j)
                acc[i][j] = __builtin_amdgcn_mfma_f32_16x16x32_bf16(
                    af[i], bfr[j], acc[i][j], 0, 0, 0);
        __syncthreads();
    }

    #pragma unroll
    for (int i = 0; i < 4; ++i) {
        #pragma unroll
        for (int j = 0; j < 4; ++j) {
            const int col   = col0 + wc + j * 16 + (lane & 15);
            const int rbase = row0 + wr + i * 16 + (lane >> 4) * 4;
            #pragma unroll
            for (int r = 0; r < 4; ++r)
                Cb[(size_t)(rbase + r) * DDIM + col] = acc[i][j][r];
        }
    }
}

extern "C" void kernel_launch(void* const* d_in, const int* in_sizes, int n_in,
                              void* d_out, int out_size, void* d_ws, size_t ws_size,
                              hipStream_t stream) {
    const float* Q       = (const float*)d_in[0];
    const float* M       = (const float*)d_in[1];
    const int*   lengths = (const int*)d_in[2];

    float* ctx   = (float*)d_out;                        // [N, TD, D]
    float* align = ctx + (size_t)NB * TDIM * DDIM;       // [N, TD, TE]

    dim3 blk(256);
    // 1) raw scaled scores -> alignments region (used as scratch)
    scores_kernel<<<dim3(TDIM / 128, TEDIM / 128, NB), blk, 0, stream>>>(Q, M, align);
    // 2) masked softmax in place
    softmax_kernel<<<dim3(NB * TDIM), blk, 0, stream>>>(align, lengths);
    // 3) contexts = A @ M
    contexts_kernel<<<dim3(TDIM / 128, DDIM / 128, NB), blk, 0, stream>>>(align, M, ctx);
}

// Round 2
// 320.149 us; speedup vs baseline: 1.3251x; 1.3251x over previous
//
#include <hip/hip_runtime.h>
#include <hip/hip_bf16.h>

// DotProductAttention: N=8, TD=1024, TE=2048, D=1024, fp32 in/out.
// Pipeline:
//   1) cast Q -> Qb (bf16)
//   2) transpose+cast M -> Mb (bf16 [s][d]) and Mt (bf16 [d][s])
//   3) scores GEMM (m97-style, global_load_lds): S = Qb·Mbᵀ / 32  -> align (fp32)
//   4) masked softmax in place on align; also emits Pb (bf16)
//   5) contexts GEMM: C = Pb·Mtᵀ  (= P·M)
#define NB 8
#define TDIM 1024
#define TEDIM 2048
#define DDIM 1024

typedef __bf16 bf16x8 __attribute__((ext_vector_type(8)));
typedef float f32x4 __attribute__((ext_vector_type(4)));
typedef unsigned short us8 __attribute__((ext_vector_type(8)));

static __device__ __forceinline__ void gld_lds16(const __bf16* g, __bf16* l) {
    __builtin_amdgcn_global_load_lds(
        (const __attribute__((address_space(1))) void*)g,
        (__attribute__((address_space(3))) void*)l,
        16, 0, 0);
}

static __device__ __forceinline__ unsigned short bf16_bits(float f) {
    __bf16 h = (__bf16)f;
    return __builtin_bit_cast(unsigned short, h);
}

// ---------------------------------------------------------------------------
// fp32 -> bf16 elementwise cast, 8 elems/thread
// ---------------------------------------------------------------------------
__global__ __launch_bounds__(256) void cast_bf16_kernel(
    const float* __restrict__ src, __bf16* __restrict__ dst)
{
    const size_t i = ((size_t)blockIdx.x * 256 + threadIdx.x) * 8;
    float4 a = *reinterpret_cast<const float4*>(&src[i]);
    float4 b = *reinterpret_cast<const float4*>(&src[i + 4]);
    us8 o;
    o[0] = bf16_bits(a.x); o[1] = bf16_bits(a.y);
    o[2] = bf16_bits(a.z); o[3] = bf16_bits(a.w);
    o[4] = bf16_bits(b.x); o[5] = bf16_bits(b.y);
    o[6] = bf16_bits(b.z); o[7] = bf16_bits(b.w);
    *reinterpret_cast<us8*>(&dst[i]) = o;
}

// ---------------------------------------------------------------------------
// M fp32 [n][s][d] -> Mb bf16 [n][s][d] and Mt bf16 [n][d][s]
// 64x64 tiles through padded LDS (conflict-free column reads).
// ---------------------------------------------------------------------------
__global__ __launch_bounds__(256) void transpose_cast_m_kernel(
    const float* __restrict__ M, __bf16* __restrict__ Mb,
    __bf16* __restrict__ Mt)
{
    const int n  = blockIdx.z;
    const int s0 = blockIdx.x * 64;
    const int d0 = blockIdx.y * 64;
    const float* Mn  = M  + (size_t)n * TEDIM * DDIM;
    __bf16*      Mbn = Mb + (size_t)n * TEDIM * DDIM;
    __bf16*      Mtn = Mt + (size_t)n * DDIM * TEDIM;

    __shared__ float tile[64][65];
    const int t = threadIdx.x;

    #pragma unroll
    for (int j = 0; j < 4; ++j) {
        const int flat = j * 256 + t;
        const int r  = flat >> 4;           // 64 rows, 16 float4/row
        const int c4 = (flat & 15) * 4;
        float4 v = *reinterpret_cast<const float4*>(
            &Mn[(size_t)(s0 + r) * DDIM + d0 + c4]);
        tile[r][c4 + 0] = v.x; tile[r][c4 + 1] = v.y;
        tile[r][c4 + 2] = v.z; tile[r][c4 + 3] = v.w;
        ushort4 o;
        o.x = bf16_bits(v.x); o.y = bf16_bits(v.y);
        o.z = bf16_bits(v.z); o.w = bf16_bits(v.w);
        *reinterpret_cast<ushort4*>(&Mbn[(size_t)(s0 + r) * DDIM + d0 + c4]) = o;
    }
    __syncthreads();

    // write transposed: thread t -> row d0+dr, cols s0+sc0 .. +15
    const int dr  = t >> 2;
    const int sc0 = (t & 3) * 16;
    us8 o0, o1;
    #pragma unroll
    for (int i = 0; i < 8; ++i)  o0[i] = bf16_bits(tile[sc0 + i][dr]);
    #pragma unroll
    for (int i = 0; i < 8; ++i)  o1[i] = bf16_bits(tile[sc0 + 8 + i][dr]);
    __bf16* dst = &Mtn[(size_t)(d0 + dr) * TEDIM + s0 + sc0];
    *reinterpret_cast<us8*>(dst)     = o0;
    *reinterpret_cast<us8*>(dst + 8) = o1;
}

// ---------------------------------------------------------------------------
// m97-style bf16 GEMM, both operands K-major (C = A · Bᵀ).
// 128x128 tile, BK=32, 4 waves (64x64 each), global_load_lds width-16.
// ---------------------------------------------------------------------------
template<int LDA, int LDB, int LDC, int KDIM, bool SCALE>
__global__ __launch_bounds__(256) void gemm_bt_kernel(
    const __bf16* __restrict__ A, const __bf16* __restrict__ B,
    float* __restrict__ C)
{
    const int n    = blockIdx.z;
    const int row0 = blockIdx.x * 128;
    const int col0 = blockIdx.y * 128;

    const __bf16* Ab = A + (size_t)n * gridDim.x * 128 * LDA + (size_t)row0 * LDA;
    const __bf16* Bb = B + (size_t)n * gridDim.y * 128 * LDB + (size_t)col0 * LDB;
    float*        Cb = C + (size_t)n * gridDim.x * 128 * LDC;

    __shared__ __align__(16) __bf16 As[128 * 32];
    __shared__ __align__(16) __bf16 Bs[128 * 32];

    const int t    = threadIdx.x;
    const int lane = t & 63;
    const int w    = t >> 6;
    const int wr   = (w >> 1) * 64;
    const int wc   = (w & 1) * 64;

    f32x4 acc[4][4] = {};

    for (int k0 = 0; k0 < KDIM; k0 += 32) {
        // stage: 128x32 bf16 per buffer = 8 KB; 256 thr x 16 B x 2 loads
        #pragma unroll
        for (int j = 0; j < 2; ++j) {
            const int tt = j * 256 + t;
            const int r  = tt >> 2;
            const int c  = (tt & 3) * 8;
            gld_lds16(Ab + (size_t)r * LDA + k0 + c, &As[tt * 8]);
            gld_lds16(Bb + (size_t)r * LDB + k0 + c, &Bs[tt * 8]);
        }
        __syncthreads();   // compiler drains vmcnt before barrier

        bf16x8 af[4], bfr[4];
        #pragma unroll
        for (int i = 0; i < 4; ++i)
            af[i] = *reinterpret_cast<const bf16x8*>(
                &As[(wr + i * 16 + (lane & 15)) * 32 + (lane >> 4) * 8]);
        #pragma unroll
        for (int j = 0; j < 4; ++j)
            bfr[j] = *reinterpret_cast<const bf16x8*>(
                &Bs[(wc + j * 16 + (lane & 15)) * 32 + (lane >> 4) * 8]);

        #pragma unroll
        for (int i = 0; i < 4; ++i)
            #pragma unroll
            for (int j = 0; j < 4; ++j)
                acc[i][j] = __builtin_amdgcn_mfma_f32_16x16x32_bf16(
                    af[i], bfr[j], acc[i][j], 0, 0, 0);
        __syncthreads();
    }

    const float sc = SCALE ? 0.03125f : 1.0f;
    #pragma unroll
    for (int i = 0; i < 4; ++i) {
        #pragma unroll
        for (int j = 0; j < 4; ++j) {
            const int col   = col0 + wc + j * 16 + (lane & 15);
            const int rbase = row0 + wr + i * 16 + (lane >> 4) * 4;
            #pragma unroll
            for (int r = 0; r < 4; ++r)
                Cb[(size_t)(rbase + r) * LDC + col] = acc[i][j][r] * sc;
        }
    }
}

// ---------------------------------------------------------------------------
// masked softmax over each row (TE=2048), in place; also writes bf16 copy.
// One 256-thread block per row, 8 elems/thread.
// ---------------------------------------------------------------------------
__global__ __launch_bounds__(256) void softmax_kernel(
    float* __restrict__ S, __bf16* __restrict__ Pb,
    const int* __restrict__ len_p)
{
    const int row = blockIdx.x;          // n*TD + t
    const int n   = row >> 10;           // TD = 1024
    const int len = len_p[n];
    float*  Sr  = S  + (size_t)row * TEDIM;
    __bf16* Pr  = Pb + (size_t)row * TEDIM;

    const int t    = threadIdx.x;
    const int lane = t & 63;
    const int w    = t >> 6;
    const int s0   = t * 8;

    float4 a = *reinterpret_cast<const float4*>(&Sr[s0]);
    float4 b = *reinterpret_cast<const float4*>(&Sr[s0 + 4]);
    float v[8] = {a.x, a.y, a.z, a.w, b.x, b.y, b.z, b.w};
    #pragma unroll
    for (int i = 0; i < 8; ++i)
        if (s0 + i >= len) v[i] = -INFINITY;

    float mx = v[0];
    #pragma unroll
    for (int i = 1; i < 8; ++i) mx = fmaxf(mx, v[i]);
    #pragma unroll
    for (int off = 32; off; off >>= 1) mx = fmaxf(mx, __shfl_xor(mx, off));

    __shared__ float redm[4], reds[4];
    if (lane == 0) redm[w] = mx;
    __syncthreads();
    mx = fmaxf(fmaxf(redm[0], redm[1]), fmaxf(redm[2], redm[3]));

    float e[8];
    float sum = 0.f;
    #pragma unroll
    for (int i = 0; i < 8; ++i) { e[i] = __expf(v[i] - mx); sum += e[i]; }
    #pragma unroll
    for (int off = 32; off; off >>= 1) sum += __shfl_xor(sum, off);
    if (lane == 0) reds[w] = sum;
    __syncthreads();
    sum = reds[0] + reds[1] + reds[2] + reds[3];

    const float r = 1.0f / sum;
    float4 oa = {e[0] * r, e[1] * r, e[2] * r, e[3] * r};
    float4 ob = {e[4] * r, e[5] * r, e[6] * r, e[7] * r};
    *reinterpret_cast<float4*>(&Sr[s0])     = oa;
    *reinterpret_cast<float4*>(&Sr[s0 + 4]) = ob;

    us8 o;
    o[0] = bf16_bits(oa.x); o[1] = bf16_bits(oa.y);
    o[2] = bf16_bits(oa.z); o[3] = bf16_bits(oa.w);
    o[4] = bf16_bits(ob.x); o[5] = bf16_bits(ob.y);
    o[6] = bf16_bits(ob.z); o[7] = bf16_bits(ob.w);
    *reinterpret_cast<us8*>(&Pr[s0]) = o;
}

extern "C" void kernel_launch(void* const* d_in, const int* in_sizes, int n_in,
                              void* d_out, int out_size, void* d_ws, size_t ws_size,
                              hipStream_t stream) {
    const float* Q       = (const float*)d_in[0];
    const float* M       = (const float*)d_in[1];
    const int*   lengths = (const int*)d_in[2];

    float* ctx   = (float*)d_out;                        // [N, TD, D]
    float* align = ctx + (size_t)NB * TDIM * DDIM;       // [N, TD, TE]

    // workspace layout (bf16 elements)
    __bf16* Qb = (__bf16*)d_ws;                          // [N, TD, D]   16.8 MB
    __bf16* Mb = Qb + (size_t)NB * TDIM * DDIM;          // [N, TE, D]   33.6 MB
    __bf16* Mt = Mb + (size_t)NB * TEDIM * DDIM;         // [N, D, TE]   33.6 MB
    __bf16* Pb = Mt + (size_t)NB * DDIM * TEDIM;         // [N, TD, TE]  33.6 MB

    dim3 blk(256);
    // 1) Q -> bf16
    cast_bf16_kernel<<<dim3(NB * TDIM * DDIM / (8 * 256)), blk, 0, stream>>>(Q, Qb);
    // 2) M -> Mb (bf16) + Mt (bf16 transposed)
    transpose_cast_m_kernel<<<dim3(TEDIM / 64, DDIM / 64, NB), blk, 0, stream>>>(M, Mb, Mt);
    // 3) scores: S = Qb·Mbᵀ / 32   (A K-major lda=D, B K-major ldb=D, C ldc=TE)
    gemm_bt_kernel<DDIM, DDIM, TEDIM, DDIM, true>
        <<<dim3(TDIM / 128, TEDIM / 128, NB), blk, 0, stream>>>(Qb, Mb, align);
    // 4) masked softmax in place + bf16 copy
    softmax_kernel<<<dim3(NB * TDIM), blk, 0, stream>>>(align, Pb, lengths);
    // 5) contexts: C = Pb·Mtᵀ = P·M  (A lda=TE, B ldb=TE, C ldc=D)
    gemm_bt_kernel<TEDIM, TEDIM, DDIM, TEDIM, false>
        <<<dim3(TDIM / 128, DDIM / 128, NB), blk, 0, stream>>>(Pb, Mt, ctx);
}

// Round 3
// 296.284 us; speedup vs baseline: 1.4318x; 1.0805x over previous
//
#include <hip/hip_runtime.h>
#include <hip/hip_bf16.h>

// DotProductAttention: N=8, TD=1024, TE=2048, D=1024, fp32 in/out.
// Pipeline:
//   1) cast Q -> Qb (bf16)
//   2) transpose+cast M -> Mb (bf16 [s][d]) and Mt (bf16 [d][s])
//   3) scores GEMM (m97-style + XCD swizzle): Praw = bf16(Qb·Mbᵀ / 32)
//   4) masked softmax: reads Praw, writes align (fp32) + Pb (bf16, in place)
//   5) contexts GEMM: C = Pb·Mtᵀ  (= P·M)
#define NB 8
#define TDIM 1024
#define TEDIM 2048
#define DDIM 1024

typedef __bf16 bf16x8 __attribute__((ext_vector_type(8)));
typedef float f32x4 __attribute__((ext_vector_type(4)));
typedef unsigned short us8 __attribute__((ext_vector_type(8)));

static __device__ __forceinline__ void gld_lds16(const __bf16* g, __bf16* l) {
    __builtin_amdgcn_global_load_lds(
        (const __attribute__((address_space(1))) void*)g,
        (__attribute__((address_space(3))) void*)l,
        16, 0, 0);
}

static __device__ __forceinline__ unsigned short bf16_bits(float f) {
    __bf16 h = (__bf16)f;
    return __builtin_bit_cast(unsigned short, h);
}
static __device__ __forceinline__ float bits_f32(unsigned short u) {
    return (float)__builtin_bit_cast(__bf16, u);
}

// ---------------------------------------------------------------------------
// fp32 -> bf16 elementwise cast, 8 elems/thread
// ---------------------------------------------------------------------------
__global__ __launch_bounds__(256) void cast_bf16_kernel(
    const float* __restrict__ src, __bf16* __restrict__ dst)
{
    const size_t i = ((size_t)blockIdx.x * 256 + threadIdx.x) * 8;
    float4 a = *reinterpret_cast<const float4*>(&src[i]);
    float4 b = *reinterpret_cast<const float4*>(&src[i + 4]);
    us8 o;
    o[0] = bf16_bits(a.x); o[1] = bf16_bits(a.y);
    o[2] = bf16_bits(a.z); o[3] = bf16_bits(a.w);
    o[4] = bf16_bits(b.x); o[5] = bf16_bits(b.y);
    o[6] = bf16_bits(b.z); o[7] = bf16_bits(b.w);
    *reinterpret_cast<us8*>(&dst[i]) = o;
}

// ---------------------------------------------------------------------------
// M fp32 [n][s][d] -> Mb bf16 [n][s][d] and Mt bf16 [n][d][s]
// 64x64 tiles through padded LDS.
// ---------------------------------------------------------------------------
__global__ __launch_bounds__(256) void transpose_cast_m_kernel(
    const float* __restrict__ M, __bf16* __restrict__ Mb,
    __bf16* __restrict__ Mt)
{
    const int n  = blockIdx.z;
    const int s0 = blockIdx.x * 64;
    const int d0 = blockIdx.y * 64;
    const float* Mn  = M  + (size_t)n * TEDIM * DDIM;
    __bf16*      Mbn = Mb + (size_t)n * TEDIM * DDIM;
    __bf16*      Mtn = Mt + (size_t)n * DDIM * TEDIM;

    __shared__ float tile[64][65];
    const int t = threadIdx.x;

    #pragma unroll
    for (int j = 0; j < 4; ++j) {
        const int flat = j * 256 + t;
        const int r  = flat >> 4;
        const int c4 = (flat & 15) * 4;
        float4 v = *reinterpret_cast<const float4*>(
            &Mn[(size_t)(s0 + r) * DDIM + d0 + c4]);
        tile[r][c4 + 0] = v.x; tile[r][c4 + 1] = v.y;
        tile[r][c4 + 2] = v.z; tile[r][c4 + 3] = v.w;
        ushort4 o;
        o.x = bf16_bits(v.x); o.y = bf16_bits(v.y);
        o.z = bf16_bits(v.z); o.w = bf16_bits(v.w);
        *reinterpret_cast<ushort4*>(&Mbn[(size_t)(s0 + r) * DDIM + d0 + c4]) = o;
    }
    __syncthreads();

    const int dr  = t >> 2;
    const int sc0 = (t & 3) * 16;
    us8 o0, o1;
    #pragma unroll
    for (int i = 0; i < 8; ++i)  o0[i] = bf16_bits(tile[sc0 + i][dr]);
    #pragma unroll
    for (int i = 0; i < 8; ++i)  o1[i] = bf16_bits(tile[sc0 + 8 + i][dr]);
    __bf16* dst = &Mtn[(size_t)(d0 + dr) * TEDIM + s0 + sc0];
    *reinterpret_cast<us8*>(dst)     = o0;
    *reinterpret_cast<us8*>(dst + 8) = o1;
}

// ---------------------------------------------------------------------------
// m97-style bf16 GEMM, both operands K-major (C = A · Bᵀ).
// 128x128 tile, BK=32, 4 waves, global_load_lds width-16.
// XCD swizzle: batch n = L&7 (one batch per XCD, panels stay in 4MB L2);
// within batch, GR-row groups, col-outer/row-inner.
// ---------------------------------------------------------------------------
template<int LDA, int LDB, int LDC, int KDIM, int GX, int GY, int GR,
         bool SCALE, bool OUTBF16>
__global__ __launch_bounds__(256) void gemm_bt_kernel(
    const __bf16* __restrict__ A, const __bf16* __restrict__ B,
    void* __restrict__ Cv)
{
    constexpr int PER_B = GX * GY;
    const int L   = blockIdx.x + GX * (blockIdx.y + GY * blockIdx.z);
    const int n   = L & 7;                 // chunk-per-XCD: nwg = PER_B*8
    const int rem = L >> 3;                // [0, PER_B)
    const int rg  = rem / (GR * GY);
    const int r2  = rem % (GR * GY);
    const int row0 = (rg * GR + (r2 % GR)) * 128;
    const int col0 = (r2 / GR) * 128;

    const __bf16* Ab = A + (size_t)n * GX * 128 * LDA + (size_t)row0 * LDA;
    const __bf16* Bb = B + (size_t)n * GY * 128 * LDB + (size_t)col0 * LDB;

    __shared__ __align__(16) __bf16 As[128 * 32];
    __shared__ __align__(16) __bf16 Bs[128 * 32];

    const int t    = threadIdx.x;
    const int lane = t & 63;
    const int w    = t >> 6;
    const int wr   = (w >> 1) * 64;
    const int wc   = (w & 1) * 64;

    f32x4 acc[4][4] = {};

    for (int k0 = 0; k0 < KDIM; k0 += 32) {
        #pragma unroll
        for (int j = 0; j < 2; ++j) {
            const int tt = j * 256 + t;
            const int r  = tt >> 2;
            const int c  = (tt & 3) * 8;
            gld_lds16(Ab + (size_t)r * LDA + k0 + c, &As[tt * 8]);
            gld_lds16(Bb + (size_t)r * LDB + k0 + c, &Bs[tt * 8]);
        }
        __syncthreads();

        bf16x8 af[4], bfr[4];
        #pragma unroll
        for (int i = 0; i < 4; ++i)
            af[i] = *reinterpret_cast<const bf16x8*>(
                &As[(wr + i * 16 + (lane & 15)) * 32 + (lane >> 4) * 8]);
        #pragma unroll
        for (int j = 0; j < 4; ++j)
            bfr[j] = *reinterpret_cast<const bf16x8*>(
                &Bs[(wc + j * 16 + (lane & 15)) * 32 + (lane >> 4) * 8]);

        #pragma unroll
        for (int i = 0; i < 4; ++i)
            #pragma unroll
            for (int j = 0; j < 4; ++j)
                acc[i][j] = __builtin_amdgcn_mfma_f32_16x16x32_bf16(
                    af[i], bfr[j], acc[i][j], 0, 0, 0);
        __syncthreads();
    }

    const float sc = SCALE ? 0.03125f : 1.0f;
    #pragma unroll
    for (int i = 0; i < 4; ++i) {
        #pragma unroll
        for (int j = 0; j < 4; ++j) {
            const int col   = col0 + wc + j * 16 + (lane & 15);
            const int rbase = row0 + wr + i * 16 + (lane >> 4) * 4;
            #pragma unroll
            for (int r = 0; r < 4; ++r) {
                const size_t idx =
                    (size_t)n * GX * 128 * LDC + (size_t)(rbase + r) * LDC + col;
                if constexpr (OUTBF16)
                    ((__bf16*)Cv)[idx] = (__bf16)(acc[i][j][r] * sc);
                else
                    ((float*)Cv)[idx] = acc[i][j][r] * sc;
            }
        }
    }
}

// ---------------------------------------------------------------------------
// masked softmax: reads raw bf16 scores from P (in place), writes
// normalized fp32 to Sout and normalized bf16 back to P.
// One 256-thread block per row, 8 elems/thread.
// ---------------------------------------------------------------------------
__global__ __launch_bounds__(256) void softmax_kernel(
    __bf16* __restrict__ P, float* __restrict__ Sout,
    const int* __restrict__ len_p)
{
    const int row = blockIdx.x;          // n*TD + t
    const int n   = row >> 10;           // TD = 1024
    const int len = len_p[n];
    __bf16* Pr = P    + (size_t)row * TEDIM;
    float*  Sr = Sout + (size_t)row * TEDIM;

    const int t    = threadIdx.x;
    const int lane = t & 63;
    const int w    = t >> 6;
    const int s0   = t * 8;

    us8 raw = *reinterpret_cast<const us8*>(&Pr[s0]);
    float v[8];
    #pragma unroll
    for (int i = 0; i < 8; ++i) {
        v[i] = bits_f32(raw[i]);
        if (s0 + i >= len) v[i] = -INFINITY;
    }

    float mx = v[0];
    #pragma unroll
    for (int i = 1; i < 8; ++i) mx = fmaxf(mx, v[i]);
    #pragma unroll
    for (int off = 32; off; off >>= 1) mx = fmaxf(mx, __shfl_xor(mx, off));

    __shared__ float redm[4], reds[4];
    if (lane == 0) redm[w] = mx;
    __syncthreads();
    mx = fmaxf(fmaxf(redm[0], redm[1]), fmaxf(redm[2], redm[3]));

    float e[8];
    float sum = 0.f;
    #pragma unroll
    for (int i = 0; i < 8; ++i) { e[i] = __expf(v[i] - mx); sum += e[i]; }
    #pragma unroll
    for (int off = 32; off; off >>= 1) sum += __shfl_xor(sum, off);
    if (lane == 0) reds[w] = sum;
    __syncthreads();
    sum = reds[0] + reds[1] + reds[2] + reds[3];

    const float r = 1.0f / sum;
    float p[8];
    #pragma unroll
    for (int i = 0; i < 8; ++i) p[i] = e[i] * r;

    float4 oa = {p[0], p[1], p[2], p[3]};
    float4 ob = {p[4], p[5], p[6], p[7]};
    *reinterpret_cast<float4*>(&Sr[s0])     = oa;
    *reinterpret_cast<float4*>(&Sr[s0 + 4]) = ob;

    us8 o;
    #pragma unroll
    for (int i = 0; i < 8; ++i) o[i] = bf16_bits(p[i]);
    *reinterpret_cast<us8*>(&Pr[s0]) = o;
}

extern "C" void kernel_launch(void* const* d_in, const int* in_sizes, int n_in,
                              void* d_out, int out_size, void* d_ws, size_t ws_size,
                              hipStream_t stream) {
    const float* Q       = (const float*)d_in[0];
    const float* M       = (const float*)d_in[1];
    const int*   lengths = (const int*)d_in[2];

    float* ctx   = (float*)d_out;                        // [N, TD, D]
    float* align = ctx + (size_t)NB * TDIM * DDIM;       // [N, TD, TE]

    // workspace (bf16 elements)
    __bf16* Qb = (__bf16*)d_ws;                          // [N, TD, D]
    __bf16* Mb = Qb + (size_t)NB * TDIM * DDIM;          // [N, TE, D]
    __bf16* Mt = Mb + (size_t)NB * TEDIM * DDIM;         // [N, D, TE]
    __bf16* Pb = Mt + (size_t)NB * DDIM * TEDIM;         // [N, TD, TE]

    dim3 blk(256);
    // 1) Q -> bf16
    cast_bf16_kernel<<<dim3(NB * TDIM * DDIM / (8 * 256)), blk, 0, stream>>>(Q, Qb);
    // 2) M -> Mb + Mt
    transpose_cast_m_kernel<<<dim3(TEDIM / 64, DDIM / 64, NB), blk, 0, stream>>>(M, Mb, Mt);
    // 3) raw scaled scores -> Pb (bf16). GX=8 rows, GY=16 cols, GR=8.
    gemm_bt_kernel<DDIM, DDIM, TEDIM, DDIM, 8, 16, 8, true, true>
        <<<dim3(8, 16, NB), blk, 0, stream>>>(Qb, Mb, (void*)Pb);
    // 4) masked softmax: Pb raw -> align (fp32) + Pb (bf16 normalized)
    softmax_kernel<<<dim3(NB * TDIM), blk, 0, stream>>>(Pb, align, lengths);
    // 5) contexts: C = Pb·Mtᵀ. GX=8 rows, GY=8 cols, GR=4.
    gemm_bt_kernel<TEDIM, TEDIM, DDIM, TEDIM, 8, 8, 4, false, false>
        <<<dim3(8, 8, NB), blk, 0, stream>>>(Pb, Mt, (void*)ctx);
}

// Round 4
// 287.976 us; speedup vs baseline: 1.4731x; 1.0288x over previous
//
#include <hip/hip_runtime.h>
#include <hip/hip_bf16.h>

// DotProductAttention: N=8, TD=1024, TE=2048, D=1024, fp32 in/out.
// Pipeline (mask-aware):
//   1) cast Q -> Qb (bf16)
//   2) transpose+cast M -> Mb (bf16 [s][d]) and Mt (bf16 [d][s]); skip s>=len
//   3) scores GEMM: Praw = bf16(Qb·Mbᵀ/32); skip col-tiles with col0>=len
//   4) masked softmax: Praw -> align (fp32) + Pb (bf16 normalized, zeros tail)
//   5) contexts GEMM: C = Pb·Mtᵀ with K bounded by roundup(len,32)
#define NB 8
#define TDIM 1024
#define TEDIM 2048
#define DDIM 1024

typedef __bf16 bf16x8 __attribute__((ext_vector_type(8)));
typedef float f32x4 __attribute__((ext_vector_type(4)));
typedef unsigned short us8 __attribute__((ext_vector_type(8)));

static __device__ __forceinline__ void gld_lds16(const __bf16* g, __bf16* l) {
    __builtin_amdgcn_global_load_lds(
        (const __attribute__((address_space(1))) void*)g,
        (__attribute__((address_space(3))) void*)l,
        16, 0, 0);
}

static __device__ __forceinline__ unsigned short bf16_bits(float f) {
    __bf16 h = (__bf16)f;
    return __builtin_bit_cast(unsigned short, h);
}
static __device__ __forceinline__ float bits_f32(unsigned short u) {
    return (float)__builtin_bit_cast(__bf16, u);
}

// ---------------------------------------------------------------------------
// fp32 -> bf16 elementwise cast, 8 elems/thread
// ---------------------------------------------------------------------------
__global__ __launch_bounds__(256) void cast_bf16_kernel(
    const float* __restrict__ src, __bf16* __restrict__ dst)
{
    const size_t i = ((size_t)blockIdx.x * 256 + threadIdx.x) * 8;
    float4 a = *reinterpret_cast<const float4*>(&src[i]);
    float4 b = *reinterpret_cast<const float4*>(&src[i + 4]);
    us8 o;
    o[0] = bf16_bits(a.x); o[1] = bf16_bits(a.y);
    o[2] = bf16_bits(a.z); o[3] = bf16_bits(a.w);
    o[4] = bf16_bits(b.x); o[5] = bf16_bits(b.y);
    o[6] = bf16_bits(b.z); o[7] = bf16_bits(b.w);
    *reinterpret_cast<us8*>(&dst[i]) = o;
}

// ---------------------------------------------------------------------------
// M fp32 [n][s][d] -> Mb bf16 [n][s][d] and Mt bf16 [n][d][s]
// 64x64 tiles through padded LDS. Tiles with s0 >= len[n] have no consumer.
// ---------------------------------------------------------------------------
__global__ __launch_bounds__(256) void transpose_cast_m_kernel(
    const float* __restrict__ M, __bf16* __restrict__ Mb,
    __bf16* __restrict__ Mt, const int* __restrict__ len_p)
{
    const int n  = blockIdx.z;
    const int s0 = blockIdx.x * 64;
    if (s0 >= len_p[n]) return;          // dead region: never read downstream
    const int d0 = blockIdx.y * 64;
    const float* Mn  = M  + (size_t)n * TEDIM * DDIM;
    __bf16*      Mbn = Mb + (size_t)n * TEDIM * DDIM;
    __bf16*      Mtn = Mt + (size_t)n * DDIM * TEDIM;

    __shared__ float tile[64][65];
    const int t = threadIdx.x;

    #pragma unroll
    for (int j = 0; j < 4; ++j) {
        const int flat = j * 256 + t;
        const int r  = flat >> 4;
        const int c4 = (flat & 15) * 4;
        float4 v = *reinterpret_cast<const float4*>(
            &Mn[(size_t)(s0 + r) * DDIM + d0 + c4]);
        tile[r][c4 + 0] = v.x; tile[r][c4 + 1] = v.y;
        tile[r][c4 + 2] = v.z; tile[r][c4 + 3] = v.w;
        ushort4 o;
        o.x = bf16_bits(v.x); o.y = bf16_bits(v.y);
        o.z = bf16_bits(v.z); o.w = bf16_bits(v.w);
        *reinterpret_cast<ushort4*>(&Mbn[(size_t)(s0 + r) * DDIM + d0 + c4]) = o;
    }
    __syncthreads();

    const int dr  = t >> 2;
    const int sc0 = (t & 3) * 16;
    us8 o0, o1;
    #pragma unroll
    for (int i = 0; i < 8; ++i)  o0[i] = bf16_bits(tile[sc0 + i][dr]);
    #pragma unroll
    for (int i = 0; i < 8; ++i)  o1[i] = bf16_bits(tile[sc0 + 8 + i][dr]);
    __bf16* dst = &Mtn[(size_t)(d0 + dr) * TEDIM + s0 + sc0];
    *reinterpret_cast<us8*>(dst)     = o0;
    *reinterpret_cast<us8*>(dst + 8) = o1;
}

// ---------------------------------------------------------------------------
// Scores GEMM: Praw[t][s] = bf16(dot(Qb[t],Mb[s]) / 32).  m97 structure.
// Col-tile pairing {x, 15-x} per XCD (x = blockIdx.x & 7) balances the
// mask-skip (high cols die when col0 >= len). Skipped tiles never written.
// ---------------------------------------------------------------------------
__global__ __launch_bounds__(256) void scores_kernel(
    const __bf16* __restrict__ Qb, const __bf16* __restrict__ Mb,
    __bf16* __restrict__ Pb, const int* __restrict__ len_p)
{
    const int n   = blockIdx.z;
    const int len = len_p[n];
    const int xc  = blockIdx.x;                      // 0..15, XCD = xc & 7
    const int ct  = (xc < 8) ? xc : 23 - xc;         // pair {x, 15-x}
    const int col0 = ct * 128;
    if (col0 >= len) return;                         // fully masked: dead
    const int row0 = blockIdx.y * 128;

    const __bf16* Ab = Qb + (size_t)n * TDIM * DDIM + (size_t)row0 * DDIM;
    const __bf16* Bb = Mb + (size_t)n * TEDIM * DDIM + (size_t)col0 * DDIM;
    __bf16*       Cb = Pb + (size_t)n * TDIM * TEDIM;

    __shared__ __align__(16) __bf16 As[128 * 32];
    __shared__ __align__(16) __bf16 Bs[128 * 32];

    const int t    = threadIdx.x;
    const int lane = t & 63;
    const int w    = t >> 6;
    const int wr   = (w >> 1) * 64;
    const int wc   = (w & 1) * 64;

    f32x4 acc[4][4] = {};

    for (int k0 = 0; k0 < DDIM; k0 += 32) {
        #pragma unroll
        for (int j = 0; j < 2; ++j) {
            const int tt = j * 256 + t;
            const int r  = tt >> 2;
            const int c  = (tt & 3) * 8;
            gld_lds16(Ab + (size_t)r * DDIM + k0 + c, &As[tt * 8]);
            gld_lds16(Bb + (size_t)r * DDIM + k0 + c, &Bs[tt * 8]);
        }
        __syncthreads();

        bf16x8 af[4], bfr[4];
        #pragma unroll
        for (int i = 0; i < 4; ++i)
            af[i] = *reinterpret_cast<const bf16x8*>(
                &As[(wr + i * 16 + (lane & 15)) * 32 + (lane >> 4) * 8]);
        #pragma unroll
        for (int j = 0; j < 4; ++j)
            bfr[j] = *reinterpret_cast<const bf16x8*>(
                &Bs[(wc + j * 16 + (lane & 15)) * 32 + (lane >> 4) * 8]);

        #pragma unroll
        for (int i = 0; i < 4; ++i)
            #pragma unroll
            for (int j = 0; j < 4; ++j)
                acc[i][j] = __builtin_amdgcn_mfma_f32_16x16x32_bf16(
                    af[i], bfr[j], acc[i][j], 0, 0, 0);
        __syncthreads();
    }

    #pragma unroll
    for (int i = 0; i < 4; ++i) {
        #pragma unroll
        for (int j = 0; j < 4; ++j) {
            const int col   = col0 + wc + j * 16 + (lane & 15);
            const int rbase = row0 + wr + i * 16 + (lane >> 4) * 4;
            #pragma unroll
            for (int r = 0; r < 4; ++r)
                Cb[(size_t)(rbase + r) * TEDIM + col] =
                    (__bf16)(acc[i][j][r] * 0.03125f);
        }
    }
}

// ---------------------------------------------------------------------------
// Contexts GEMM: C[t][d] = sum_{s<len} P[t][s] * M[s][d] = Pb·Mtᵀ, K-bounded.
// One D-col-tile per XCD (blockIdx.x & 7): per-XCD work = sum_n len_n
// (perfectly balanced) and the Mt col panel stays L2-resident.
// ---------------------------------------------------------------------------
__global__ __launch_bounds__(256) void contexts_kernel(
    const __bf16* __restrict__ Pb, const __bf16* __restrict__ Mt,
    float* __restrict__ C, const int* __restrict__ len_p)
{
    const int n    = blockIdx.z;
    const int len  = len_p[n];
    const int kmax = (len + 31) & ~31;               // P is exactly 0 beyond len
    const int col0 = blockIdx.x * 128;               // D cols, XCD = x & 7
    const int row0 = blockIdx.y * 128;

    const __bf16* Ab = Pb + (size_t)n * TDIM * TEDIM + (size_t)row0 * TEDIM;
    const __bf16* Bb = Mt + (size_t)n * DDIM * TEDIM + (size_t)col0 * TEDIM;
    float*        Cb = C  + (size_t)n * TDIM * DDIM;

    __shared__ __align__(16) __bf16 As[128 * 32];
    __shared__ __align__(16) __bf16 Bs[128 * 32];

    const int t    = threadIdx.x;
    const int lane = t & 63;
    const int w    = t >> 6;
    const int wr   = (w >> 1) * 64;
    const int wc   = (w & 1) * 64;

    f32x4 acc[4][4] = {};

    for (int k0 = 0; k0 < kmax; k0 += 32) {
        #pragma unroll
        for (int j = 0; j < 2; ++j) {
            const int tt = j * 256 + t;
            const int r  = tt >> 2;
            const int c  = (tt & 3) * 8;
            gld_lds16(Ab + (size_t)r * TEDIM + k0 + c, &As[tt * 8]);
            gld_lds16(Bb + (size_t)r * TEDIM + k0 + c, &Bs[tt * 8]);
        }
        __syncthreads();

        bf16x8 af[4], bfr[4];
        #pragma unroll
        for (int i = 0; i < 4; ++i)
            af[i] = *reinterpret_cast<const bf16x8*>(
                &As[(wr + i * 16 + (lane & 15)) * 32 + (lane >> 4) * 8]);
        #pragma unroll
        for (int j = 0; j < 4; ++j)
            bfr[j] = *reinterpret_cast<const bf16x8*>(
                &Bs[(wc + j * 16 + (lane & 15)) * 32 + (lane >> 4) * 8]);

        #pragma unroll
        for (int i = 0; i < 4; ++i)
            #pragma unroll
            for (int j = 0; j < 4; ++j)
                acc[i][j] = __builtin_amdgcn_mfma_f32_16x16x32_bf16(
                    af[i], bfr[j], acc[i][j], 0, 0, 0);
        __syncthreads();
    }

    #pragma unroll
    for (int i = 0; i < 4; ++i) {
        #pragma unroll
        for (int j = 0; j < 4; ++j) {
            const int col   = col0 + wc + j * 16 + (lane & 15);
            const int rbase = row0 + wr + i * 16 + (lane >> 4) * 4;
            #pragma unroll
            for (int r = 0; r < 4; ++r)
                Cb[(size_t)(rbase + r) * DDIM + col] = acc[i][j][r];
        }
    }
}

// ---------------------------------------------------------------------------
// masked softmax: reads raw bf16 scores from P (in place), writes
// normalized fp32 to Sout and normalized bf16 back to P (zeros past len).
// ---------------------------------------------------------------------------
__global__ __launch_bounds__(256) void softmax_kernel(
    __bf16* __restrict__ P, float* __restrict__ Sout,
    const int* __restrict__ len_p)
{
    const int row = blockIdx.x;          // n*TD + t
    const int n   = row >> 10;           // TD = 1024
    const int len = len_p[n];
    __bf16* Pr = P    + (size_t)row * TEDIM;
    float*  Sr = Sout + (size_t)row * TEDIM;

    const int t    = threadIdx.x;
    const int lane = t & 63;
    const int w    = t >> 6;
    const int s0   = t * 8;

    us8 raw = *reinterpret_cast<const us8*>(&Pr[s0]);
    float v[8];
    #pragma unroll
    for (int i = 0; i < 8; ++i) {
        v[i] = bits_f32(raw[i]);
        if (s0 + i >= len) v[i] = -INFINITY;
    }

    float mx = v[0];
    #pragma unroll
    for (int i = 1; i < 8; ++i) mx = fmaxf(mx, v[i]);
    #pragma unroll
    for (int off = 32; off; off >>= 1) mx = fmaxf(mx, __shfl_xor(mx, off));

    __shared__ float redm[4], reds[4];
    if (lane == 0) redm[w] = mx;
    __syncthreads();
    mx = fmaxf(fmaxf(redm[0], redm[1]), fmaxf(redm[2], redm[3]));

    float e[8];
    float sum = 0.f;
    #pragma unroll
    for (int i = 0; i < 8; ++i) { e[i] = __expf(v[i] - mx); sum += e[i]; }
    #pragma unroll
    for (int off = 32; off; off >>= 1) sum += __shfl_xor(sum, off);
    if (lane == 0) reds[w] = sum;
    __syncthreads();
    sum = reds[0] + reds[1] + reds[2] + reds[3];

    const float r = 1.0f / sum;
    float p[8];
    #pragma unroll
    for (int i = 0; i < 8; ++i) p[i] = e[i] * r;

    float4 oa = {p[0], p[1], p[2], p[3]};
    float4 ob = {p[4], p[5], p[6], p[7]};
    *reinterpret_cast<float4*>(&Sr[s0])     = oa;
    *reinterpret_cast<float4*>(&Sr[s0 + 4]) = ob;

    us8 o;
    #pragma unroll
    for (int i = 0; i < 8; ++i) o[i] = bf16_bits(p[i]);
    *reinterpret_cast<us8*>(&Pr[s0]) = o;
}

extern "C" void kernel_launch(void* const* d_in, const int* in_sizes, int n_in,
                              void* d_out, int out_size, void* d_ws, size_t ws_size,
                              hipStream_t stream) {
    const float* Q       = (const float*)d_in[0];
    const float* M       = (const float*)d_in[1];
    const int*   lengths = (const int*)d_in[2];

    float* ctx   = (float*)d_out;                        // [N, TD, D]
    float* align = ctx + (size_t)NB * TDIM * DDIM;       // [N, TD, TE]

    // workspace (bf16 elements)
    __bf16* Qb = (__bf16*)d_ws;                          // [N, TD, D]
    __bf16* Mb = Qb + (size_t)NB * TDIM * DDIM;          // [N, TE, D]
    __bf16* Mt = Mb + (size_t)NB * TEDIM * DDIM;         // [N, D, TE]
    __bf16* Pb = Mt + (size_t)NB * DDIM * TEDIM;         // [N, TD, TE]

    dim3 blk(256);
    // 1) Q -> bf16
    cast_bf16_kernel<<<dim3(NB * TDIM * DDIM / (8 * 256)), blk, 0, stream>>>(Q, Qb);
    // 2) M -> Mb + Mt (skips dead s-tiles)
    transpose_cast_m_kernel<<<dim3(TEDIM / 64, DDIM / 64, NB), blk, 0, stream>>>(
        M, Mb, Mt, lengths);
    // 3) raw scaled scores -> Pb (bf16); col-pair-per-XCD; mask-skip
    scores_kernel<<<dim3(16, TDIM / 128, NB), blk, 0, stream>>>(Qb, Mb, Pb, lengths);
    // 4) masked softmax: Pb raw -> align (fp32) + Pb (bf16 normalized)
    softmax_kernel<<<dim3(NB * TDIM), blk, 0, stream>>>(Pb, align, lengths);
    // 5) contexts: C = Pb·Mtᵀ, K bounded by roundup(len,32); col-per-XCD
    contexts_kernel<<<dim3(DDIM / 128, TDIM / 128, NB), blk, 0, stream>>>(
        Pb, Mt, ctx, lengths);
}

// Round 6
// 273.103 us; speedup vs baseline: 1.5534x; 1.0545x over previous
//
#include <hip/hip_runtime.h>
#include <hip/hip_bf16.h>

// DotProductAttention: N=8, TD=1024, TE=2048, D=1024, fp32 in/out.
// Pipeline (mask-aware, BK=64 swizzled GEMMs):
//   1) prepass: Q -> Qb (bf16); M -> Mb (bf16 [s][d]) + Mt (bf16 [d][s]), skip s>=len
//   2) scores GEMM: Praw = bf16(Qb·Mbᵀ/32); skip col-tiles with col0>=len
//   3) masked softmax: Praw -> align (fp32 full) + Pb (bf16, up to roundup(len,64))
//   4) contexts GEMM: C = Pb·Mtᵀ with K bounded by roundup(len,64)
#define NB 8
#define TDIM 1024
#define TEDIM 2048
#define DDIM 1024

typedef __bf16 bf16x8 __attribute__((ext_vector_type(8)));
typedef float f32x4 __attribute__((ext_vector_type(4)));
typedef unsigned short us8 __attribute__((ext_vector_type(8)));

static __device__ __forceinline__ void gld_lds16(const __bf16* g, __bf16* l) {
    __builtin_amdgcn_global_load_lds(
        (const __attribute__((address_space(1))) void*)g,
        (__attribute__((address_space(3))) void*)l,
        16, 0, 0);
}

static __device__ __forceinline__ unsigned short bf16_bits(float f) {
    __bf16 h = (__bf16)f;
    return __builtin_bit_cast(unsigned short, h);
}
static __device__ __forceinline__ float bits_f32(unsigned short u) {
    return (float)__builtin_bit_cast(__bf16, u);
}

// ---------------------------------------------------------------------------
// Prepass: z<8 -> M 64x64 transpose tiles (skip dead s-tiles);
//          z>=8 -> Q fp32->bf16 cast (1024 flat blocks, 32 elems/thread).
// ---------------------------------------------------------------------------
__global__ __launch_bounds__(256) void prepass_kernel(
    const float* __restrict__ Q, const float* __restrict__ M,
    __bf16* __restrict__ Qb, __bf16* __restrict__ Mb, __bf16* __restrict__ Mt,
    const int* __restrict__ len_p)
{
    const int z = blockIdx.z;
    const int t = threadIdx.x;

    if (z >= NB) {                       // ---- Q cast ----
        const int flat = (z - NB) * 512 + blockIdx.y * 32 + blockIdx.x;
        const size_t base = (size_t)flat * 8192 + (size_t)t * 8;
        #pragma unroll
        for (int c = 0; c < 4; ++c) {
            const size_t i = base + (size_t)c * 2048;
            float4 a = *reinterpret_cast<const float4*>(&Q[i]);
            float4 b = *reinterpret_cast<const float4*>(&Q[i + 4]);
            us8 o;
            o[0] = bf16_bits(a.x); o[1] = bf16_bits(a.y);
            o[2] = bf16_bits(a.z); o[3] = bf16_bits(a.w);
            o[4] = bf16_bits(b.x); o[5] = bf16_bits(b.y);
            o[6] = bf16_bits(b.z); o[7] = bf16_bits(b.w);
            *reinterpret_cast<us8*>(&Qb[i]) = o;
        }
        return;
    }

    // ---- M cast + transpose ----
    const int n  = z;
    const int s0 = blockIdx.x * 64;
    if (s0 >= len_p[n]) return;          // dead region: never read downstream
    const int d0 = blockIdx.y * 64;
    const float* Mn  = M  + (size_t)n * TEDIM * DDIM;
    __bf16*      Mbn = Mb + (size_t)n * TEDIM * DDIM;
    __bf16*      Mtn = Mt + (size_t)n * DDIM * TEDIM;

    __shared__ float tile[64][65];

    #pragma unroll
    for (int j = 0; j < 4; ++j) {
        const int flat = j * 256 + t;
        const int r  = flat >> 4;
        const int c4 = (flat & 15) * 4;
        float4 v = *reinterpret_cast<const float4*>(
            &Mn[(size_t)(s0 + r) * DDIM + d0 + c4]);
        tile[r][c4 + 0] = v.x; tile[r][c4 + 1] = v.y;
        tile[r][c4 + 2] = v.z; tile[r][c4 + 3] = v.w;
        ushort4 o;
        o.x = bf16_bits(v.x); o.y = bf16_bits(v.y);
        o.z = bf16_bits(v.z); o.w = bf16_bits(v.w);
        *reinterpret_cast<ushort4*>(&Mbn[(size_t)(s0 + r) * DDIM + d0 + c4]) = o;
    }
    __syncthreads();

    const int dr  = t >> 2;
    const int sc0 = (t & 3) * 16;
    us8 o0, o1;
    #pragma unroll
    for (int i = 0; i < 8; ++i)  o0[i] = bf16_bits(tile[sc0 + i][dr]);
    #pragma unroll
    for (int i = 0; i < 8; ++i)  o1[i] = bf16_bits(tile[sc0 + 8 + i][dr]);
    __bf16* dst = &Mtn[(size_t)(d0 + dr) * TEDIM + s0 + sc0];
    *reinterpret_cast<us8*>(dst)     = o0;
    *reinterpret_cast<us8*>(dst + 8) = o1;
}

// ---------------------------------------------------------------------------
// bf16 GEMM, both operands K-major (C = A · Bᵀ). 128x128 tile, BK=64,
// 4 waves. T2 XOR-swizzle: LDS dest linear (global_load_lds), global source
// chunk-permuted cg = (slot&7)^(r&7); reads un-swizzle with the same XOR
// (rule #21: same involution both sides). Conflict-free at 128B rows.
// COLPAIR: col-tile {x,15-x} pairing per XCD + mask-skip (scores).
// KBOUND: K-loop bounded by roundup(len,64) (contexts).
// ---------------------------------------------------------------------------
template<int LDA, int LDB, int LDC, int KDIM, long SA, long SB, long SC,
         bool COLPAIR, bool SCALE, bool OUTBF16, bool KBOUND>
__global__ __launch_bounds__(256) void gemm_kernel(
    const __bf16* __restrict__ A, const __bf16* __restrict__ B,
    void* __restrict__ Cv, const int* __restrict__ len_p)
{
    const int n   = blockIdx.z;
    const int len = len_p[n];
    int ct;
    if constexpr (COLPAIR) {
        const int xc = blockIdx.x;               // 0..15, XCD = xc & 7
        ct = (xc < 8) ? xc : 23 - xc;            // pair {x, 15-x}
        if (ct * 128 >= len) return;             // fully masked: dead
    } else {
        ct = blockIdx.x;                         // XCD = x & 7
    }
    const int col0 = ct * 128;
    const int row0 = blockIdx.y * 128;
    const int klim = KBOUND ? ((len + 63) & ~63) : KDIM;

    const __bf16* Ab = A + (size_t)n * SA + (size_t)row0 * LDA;
    const __bf16* Bb = B + (size_t)n * SB + (size_t)col0 * LDB;

    __shared__ __align__(16) __bf16 As[128 * 64];
    __shared__ __align__(16) __bf16 Bs[128 * 64];

    const int t    = threadIdx.x;
    const int lane = t & 63;
    const int w    = t >> 6;
    const int wr   = (w >> 1) * 64;
    const int wc   = (w & 1) * 64;

    f32x4 acc[4][4] = {};

    for (int k0 = 0; k0 < klim; k0 += 64) {
        // stage 128x64 bf16 per operand: 1024 16B-chunks, source-swizzled
        #pragma unroll
        for (int j = 0; j < 4; ++j) {
            const int slot = j * 256 + t;
            const int r    = slot >> 3;
            const int cg   = (slot & 7) ^ (r & 7);
            gld_lds16(Ab + (size_t)r * LDA + k0 + cg * 8, &As[slot * 8]);
            gld_lds16(Bb + (size_t)r * LDB + k0 + cg * 8, &Bs[slot * 8]);
        }
        __syncthreads();

        bf16x8 af[2][4], bfr[2][4];
        #pragma unroll
        for (int kk = 0; kk < 2; ++kk) {
            #pragma unroll
            for (int i = 0; i < 4; ++i) {
                const int rowa = wr + i * 16 + (lane & 15);
                const int ca   = (kk * 4 + (lane >> 4)) ^ (rowa & 7);
                af[kk][i] = *reinterpret_cast<const bf16x8*>(
                    &As[rowa * 64 + ca * 8]);
                const int rowb = wc + i * 16 + (lane & 15);
                const int cb   = (kk * 4 + (lane >> 4)) ^ (rowb & 7);
                bfr[kk][i] = *reinterpret_cast<const bf16x8*>(
                    &Bs[rowb * 64 + cb * 8]);
            }
        }

        #pragma unroll
        for (int kk = 0; kk < 2; ++kk)
            #pragma unroll
            for (int i = 0; i < 4; ++i)
                #pragma unroll
                for (int j = 0; j < 4; ++j)
                    acc[i][j] = __builtin_amdgcn_mfma_f32_16x16x32_bf16(
                        af[kk][i], bfr[kk][j], acc[i][j], 0, 0, 0);
        __syncthreads();
    }

    const float sc = SCALE ? 0.03125f : 1.0f;
    #pragma unroll
    for (int i = 0; i < 4; ++i) {
        #pragma unroll
        for (int j = 0; j < 4; ++j) {
            const int col   = col0 + wc + j * 16 + (lane & 15);
            const int rbase = row0 + wr + i * 16 + (lane >> 4) * 4;
            #pragma unroll
            for (int r = 0; r < 4; ++r) {
                const size_t idx = (size_t)n * SC + (size_t)(rbase + r) * LDC + col;
                if constexpr (OUTBF16)
                    ((__bf16*)Cv)[idx] = (__bf16)(acc[i][j][r] * sc);
                else
                    ((float*)Cv)[idx] = acc[i][j][r] * sc;
            }
        }
    }
}

// ---------------------------------------------------------------------------
// masked softmax: reads raw bf16 scores (only s<len), writes normalized
// fp32 to Sout (full row) + bf16 back to P (up to roundup(len,64)).
// ---------------------------------------------------------------------------
__global__ __launch_bounds__(256) void softmax_kernel(
    __bf16* __restrict__ P, float* __restrict__ Sout,
    const int* __restrict__ len_p)
{
    const int row = blockIdx.x;          // n*TD + t
    const int n   = row >> 10;           // TD = 1024
    const int len = len_p[n];
    const int kmax = (len + 63) & ~63;
    __bf16* Pr = P    + (size_t)row * TEDIM;
    float*  Sr = Sout + (size_t)row * TEDIM;

    const int t    = threadIdx.x;
    const int lane = t & 63;
    const int w    = t >> 6;
    const int s0   = t * 8;

    float v[8];
    if (s0 < len) {
        us8 raw = *reinterpret_cast<const us8*>(&Pr[s0]);
        #pragma unroll
        for (int i = 0; i < 8; ++i) {
            v[i] = bits_f32(raw[i]);
            if (s0 + i >= len) v[i] = -INFINITY;
        }
    } else {
        #pragma unroll
        for (int i = 0; i < 8; ++i) v[i] = -INFINITY;
    }

    float mx = v[0];
    #pragma unroll
    for (int i = 1; i < 8; ++i) mx = fmaxf(mx, v[i]);
    #pragma unroll
    for (int off = 32; off; off >>= 1) mx = fmaxf(mx, __shfl_xor(mx, off));

    __shared__ float redm[4], reds[4];
    if (lane == 0) redm[w] = mx;
    __syncthreads();
    mx = fmaxf(fmaxf(redm[0], redm[1]), fmaxf(redm[2], redm[3]));

    float e[8];
    float sum = 0.f;
    #pragma unroll
    for (int i = 0; i < 8; ++i) { e[i] = __expf(v[i] - mx); sum += e[i]; }
    #pragma unroll
    for (int off = 32; off; off >>= 1) sum += __shfl_xor(sum, off);
    if (lane == 0) reds[w] = sum;
    __syncthreads();
    sum = reds[0] + reds[1] + reds[2] + reds[3];

    const float r = 1.0f / sum;
    float p[8];
    #pragma unroll
    for (int i = 0; i < 8; ++i) p[i] = e[i] * r;

    float4 oa = {p[0], p[1], p[2], p[3]};
    float4 ob = {p[4], p[5], p[6], p[7]};
    *reinterpret_cast<float4*>(&Sr[s0])     = oa;   // full row (zeros in tail)
    *reinterpret_cast<float4*>(&Sr[s0 + 4]) = ob;

    if (s0 < kmax) {                     // contexts reads only [0, kmax)
        us8 o;
        #pragma unroll
        for (int i = 0; i < 8; ++i) o[i] = bf16_bits(p[i]);
        *reinterpret_cast<us8*>(&Pr[s0]) = o;
    }
}

extern "C" void kernel_launch(void* const* d_in, const int* in_sizes, int n_in,
                              void* d_out, int out_size, void* d_ws, size_t ws_size,
                              hipStream_t stream) {
    const float* Q       = (const float*)d_in[0];
    const float* M       = (const float*)d_in[1];
    const int*   lengths = (const int*)d_in[2];

    float* ctx   = (float*)d_out;                        // [N, TD, D]
    float* align = ctx + (size_t)NB * TDIM * DDIM;       // [N, TD, TE]

    // workspace (bf16 elements)
    __bf16* Qb = (__bf16*)d_ws;                          // [N, TD, D]
    __bf16* Mb = Qb + (size_t)NB * TDIM * DDIM;          // [N, TE, D]
    __bf16* Mt = Mb + (size_t)NB * TEDIM * DDIM;         // [N, D, TE]
    __bf16* Pb = Mt + (size_t)NB * DDIM * TEDIM;         // [N, TD, TE]

    dim3 blk(256);
    // 1) Q cast + M cast/transpose (dead s-tiles skipped)
    prepass_kernel<<<dim3(32, 16, 10), blk, 0, stream>>>(Q, M, Qb, Mb, Mt, lengths);
    // 2) scores: Pb_raw = bf16(Qb·Mbᵀ/32); col-pair per XCD; mask-skip
    gemm_kernel<DDIM, DDIM, TEDIM, DDIM,
                (long)TDIM * DDIM, (long)TEDIM * DDIM, (long)TDIM * TEDIM,
                true, true, true, false>
        <<<dim3(16, TDIM / 128, NB), blk, 0, stream>>>(Qb, Mb, (void*)Pb, lengths);
    // 3) masked softmax: Pb raw -> align (fp32) + Pb (bf16 normalized)
    softmax_kernel<<<dim3(NB * TDIM), blk, 0, stream>>>(Pb, align, lengths);
    // 4) contexts: C = Pb·Mtᵀ, K bounded by roundup(len,64); col-per-XCD
    gemm_kernel<TEDIM, TEDIM, DDIM, TEDIM,
                (long)TDIM * TEDIM, (long)DDIM * TEDIM, (long)TDIM * DDIM,
                false, false, false, true>
        <<<dim3(DDIM / 128, TDIM / 128, NB), blk, 0, stream>>>(Pb, Mt, (void*)ctx, lengths);
}

// Round 7
// 266.941 us; speedup vs baseline: 1.5892x; 1.0231x over previous
//
#include <hip/hip_runtime.h>
#include <hip/hip_bf16.h>

// DotProductAttention: N=8, TD=1024, TE=2048, D=1024, fp32 in/out.
// Pipeline (mask-aware, BK=64 swizzled, double-buffered GEMMs):
//   1) prepass: Q -> Qb (bf16); M -> Mb + Mt (bf16), skip s>=len
//   2) scores GEMM: Praw = bf16(Qb·Mbᵀ/32); paired col-tiles {x,15-x}/block
//   3) masked softmax: Praw -> align (fp32) + Pb (bf16, up to roundup(len,64))
//   4) contexts GEMM: C = Pb·Mtᵀ with K bounded by roundup(len,64)
#define NB 8
#define TDIM 1024
#define TEDIM 2048
#define DDIM 1024

typedef __bf16 bf16x8 __attribute__((ext_vector_type(8)));
typedef float f32x4 __attribute__((ext_vector_type(4)));
typedef unsigned short us8 __attribute__((ext_vector_type(8)));

static __device__ __forceinline__ void gld_lds16(const __bf16* g, __bf16* l) {
    __builtin_amdgcn_global_load_lds(
        (const __attribute__((address_space(1))) void*)g,
        (__attribute__((address_space(3))) void*)l,
        16, 0, 0);
}

static __device__ __forceinline__ unsigned short bf16_bits(float f) {
    __bf16 h = (__bf16)f;
    return __builtin_bit_cast(unsigned short, h);
}
static __device__ __forceinline__ float bits_f32(unsigned short u) {
    return (float)__builtin_bit_cast(__bf16, u);
}

// ---------------------------------------------------------------------------
// Prepass: z<8 -> M 64x64 transpose tiles (skip dead s-tiles);
//          z>=8 -> Q fp32->bf16 cast.
// ---------------------------------------------------------------------------
__global__ __launch_bounds__(256) void prepass_kernel(
    const float* __restrict__ Q, const float* __restrict__ M,
    __bf16* __restrict__ Qb, __bf16* __restrict__ Mb, __bf16* __restrict__ Mt,
    const int* __restrict__ len_p)
{
    const int z = blockIdx.z;
    const int t = threadIdx.x;

    if (z >= NB) {                       // ---- Q cast ----
        const int flat = (z - NB) * 512 + blockIdx.y * 32 + blockIdx.x;
        const size_t base = (size_t)flat * 8192 + (size_t)t * 8;
        #pragma unroll
        for (int c = 0; c < 4; ++c) {
            const size_t i = base + (size_t)c * 2048;
            float4 a = *reinterpret_cast<const float4*>(&Q[i]);
            float4 b = *reinterpret_cast<const float4*>(&Q[i + 4]);
            us8 o;
            o[0] = bf16_bits(a.x); o[1] = bf16_bits(a.y);
            o[2] = bf16_bits(a.z); o[3] = bf16_bits(a.w);
            o[4] = bf16_bits(b.x); o[5] = bf16_bits(b.y);
            o[6] = bf16_bits(b.z); o[7] = bf16_bits(b.w);
            *reinterpret_cast<us8*>(&Qb[i]) = o;
        }
        return;
    }

    // ---- M cast + transpose ----
    const int n  = z;
    const int s0 = blockIdx.x * 64;
    if (s0 >= len_p[n]) return;          // dead region: never read downstream
    const int d0 = blockIdx.y * 64;
    const float* Mn  = M  + (size_t)n * TEDIM * DDIM;
    __bf16*      Mbn = Mb + (size_t)n * TEDIM * DDIM;
    __bf16*      Mtn = Mt + (size_t)n * DDIM * TEDIM;

    __shared__ float tile[64][65];

    #pragma unroll
    for (int j = 0; j < 4; ++j) {
        const int flat = j * 256 + t;
        const int r  = flat >> 4;
        const int c4 = (flat & 15) * 4;
        float4 v = *reinterpret_cast<const float4*>(
            &Mn[(size_t)(s0 + r) * DDIM + d0 + c4]);
        tile[r][c4 + 0] = v.x; tile[r][c4 + 1] = v.y;
        tile[r][c4 + 2] = v.z; tile[r][c4 + 3] = v.w;
        ushort4 o;
        o.x = bf16_bits(v.x); o.y = bf16_bits(v.y);
        o.z = bf16_bits(v.z); o.w = bf16_bits(v.w);
        *reinterpret_cast<ushort4*>(&Mbn[(size_t)(s0 + r) * DDIM + d0 + c4]) = o;
    }
    __syncthreads();

    const int dr  = t >> 2;
    const int sc0 = (t & 3) * 16;
    us8 o0, o1;
    #pragma unroll
    for (int i = 0; i < 8; ++i)  o0[i] = bf16_bits(tile[sc0 + i][dr]);
    #pragma unroll
    for (int i = 0; i < 8; ++i)  o1[i] = bf16_bits(tile[sc0 + 8 + i][dr]);
    __bf16* dst = &Mtn[(size_t)(d0 + dr) * TEDIM + s0 + sc0];
    *reinterpret_cast<us8*>(dst)     = o0;
    *reinterpret_cast<us8*>(dst + 8) = o1;
}

// ---------------------------------------------------------------------------
// One 128x128 output tile, BK=64, double-buffered LDS, counted vmcnt.
// Source-swizzled staging (cg = (slot&7)^(r&7)); reads un-swizzle with the
// same XOR. Raw s_barrier + counted vmcnt(8): next tile's 8 loads stay in
// flight across the barrier (T3/T4). lgkmcnt(0)+sched_barrier before the
// tail barrier protects LDS from the next iteration's overwrite (rule #18).
// ---------------------------------------------------------------------------
template<int LDA, int LDB>
static __device__ __forceinline__ void tile_gemm_dbuf(
    const __bf16* __restrict__ Ab, const __bf16* __restrict__ Bb,
    __bf16* As, __bf16* Bs, int klim, int t, int lane, int wr, int wc,
    f32x4 (&acc)[4][4])
{
    const int nk = klim >> 6;

    auto stage = [&](int buf, int k0) {
        #pragma unroll
        for (int j = 0; j < 4; ++j) {
            const int slot = j * 256 + t;
            const int r    = slot >> 3;
            const int cg   = (slot & 7) ^ (r & 7);
            gld_lds16(Ab + (size_t)r * LDA + k0 + cg * 8,
                      As + buf * 8192 + slot * 8);
            gld_lds16(Bb + (size_t)r * LDB + k0 + cg * 8,
                      Bs + buf * 8192 + slot * 8);
        }
    };

    stage(0, 0);
    int buf = 0;
    for (int ki = 0; ki < nk; ++ki) {
        if (ki + 1 < nk) {
            stage(buf ^ 1, (ki + 1) << 6);
            asm volatile("s_waitcnt vmcnt(8)" ::: "memory");
        } else {
            asm volatile("s_waitcnt vmcnt(0)" ::: "memory");
        }
        __builtin_amdgcn_sched_barrier(0);
        __builtin_amdgcn_s_barrier();

        const __bf16* Ac = As + buf * 8192;
        const __bf16* Bc = Bs + buf * 8192;
        #pragma unroll
        for (int kk = 0; kk < 2; ++kk) {
            bf16x8 af[4], bfr[4];
            #pragma unroll
            for (int i = 0; i < 4; ++i) {
                const int rowa = wr + i * 16 + (lane & 15);
                const int ca   = (kk * 4 + (lane >> 4)) ^ (rowa & 7);
                af[i] = *reinterpret_cast<const bf16x8*>(&Ac[rowa * 64 + ca * 8]);
                const int rowb = wc + i * 16 + (lane & 15);
                const int cb   = (kk * 4 + (lane >> 4)) ^ (rowb & 7);
                bfr[i] = *reinterpret_cast<const bf16x8*>(&Bc[rowb * 64 + cb * 8]);
            }
            #pragma unroll
            for (int i = 0; i < 4; ++i)
                #pragma unroll
                for (int j = 0; j < 4; ++j)
                    acc[i][j] = __builtin_amdgcn_mfma_f32_16x16x32_bf16(
                        af[i], bfr[j], acc[i][j], 0, 0, 0);
        }
        asm volatile("s_waitcnt lgkmcnt(0)" ::: "memory");
        __builtin_amdgcn_sched_barrier(0);
        __builtin_amdgcn_s_barrier();
        buf ^= 1;
    }
}

// ---------------------------------------------------------------------------
// Scores GEMM: Praw = bf16(Qb·Mbᵀ/32). Block x in [0,8) owns the col-tile
// pair {x, 15-x} (sequential), balancing mask-skip per XCD.
// ---------------------------------------------------------------------------
__global__ __launch_bounds__(256) void scores_kernel(
    const __bf16* __restrict__ Qb, const __bf16* __restrict__ Mb,
    __bf16* __restrict__ Pb, const int* __restrict__ len_p)
{
    const int n    = blockIdx.z;
    const int len  = len_p[n];
    const int row0 = blockIdx.y * 128;

    __shared__ __align__(16) __bf16 As[2 * 128 * 64];
    __shared__ __align__(16) __bf16 Bs[2 * 128 * 64];

    const int t    = threadIdx.x;
    const int lane = t & 63;
    const int w    = t >> 6;
    const int wr   = (w >> 1) * 64;
    const int wc   = (w & 1) * 64;

    const __bf16* Ab = Qb + (size_t)n * TDIM * DDIM + (size_t)row0 * DDIM;
    __bf16*       Cb = Pb + (size_t)n * TDIM * TEDIM;

    const int cts[2] = {(int)blockIdx.x, 15 - (int)blockIdx.x};
    #pragma unroll
    for (int p = 0; p < 2; ++p) {
        const int ct   = cts[p];
        const int col0 = ct * 128;
        if (col0 >= len) continue;                   // fully masked: dead

        const __bf16* Bb = Mb + (size_t)n * TEDIM * DDIM + (size_t)col0 * DDIM;
        f32x4 acc[4][4] = {};
        tile_gemm_dbuf<DDIM, DDIM>(Ab, Bb, As, Bs, DDIM, t, lane, wr, wc, acc);

        #pragma unroll
        for (int i = 0; i < 4; ++i) {
            #pragma unroll
            for (int j = 0; j < 4; ++j) {
                const int col   = col0 + wc + j * 16 + (lane & 15);
                const int rbase = row0 + wr + i * 16 + (lane >> 4) * 4;
                #pragma unroll
                for (int r = 0; r < 4; ++r)
                    Cb[(size_t)(rbase + r) * TEDIM + col] =
                        (__bf16)(acc[i][j][r] * 0.03125f);
            }
        }
    }
}

// ---------------------------------------------------------------------------
// Contexts GEMM: C = Pb·Mtᵀ, K bounded by roundup(len,64). One D-col tile
// per XCD (blockIdx.x & 7): per-XCD work = sum_n len_n, Mt panel L2-hot.
// ---------------------------------------------------------------------------
__global__ __launch_bounds__(256) void contexts_kernel(
    const __bf16* __restrict__ Pb, const __bf16* __restrict__ Mt,
    float* __restrict__ C, const int* __restrict__ len_p)
{
    const int n    = blockIdx.z;
    const int len  = len_p[n];
    const int klim = (len + 63) & ~63;
    const int col0 = blockIdx.x * 128;               // D cols, XCD = x & 7
    const int row0 = blockIdx.y * 128;

    __shared__ __align__(16) __bf16 As[2 * 128 * 64];
    __shared__ __align__(16) __bf16 Bs[2 * 128 * 64];

    const int t    = threadIdx.x;
    const int lane = t & 63;
    const int w    = t >> 6;
    const int wr   = (w >> 1) * 64;
    const int wc   = (w & 1) * 64;

    const __bf16* Ab = Pb + (size_t)n * TDIM * TEDIM + (size_t)row0 * TEDIM;
    const __bf16* Bb = Mt + (size_t)n * DDIM * TEDIM + (size_t)col0 * TEDIM;
    float*        Cb = C  + (size_t)n * TDIM * DDIM;

    f32x4 acc[4][4] = {};
    tile_gemm_dbuf<TEDIM, TEDIM>(Ab, Bb, As, Bs, klim, t, lane, wr, wc, acc);

    #pragma unroll
    for (int i = 0; i < 4; ++i) {
        #pragma unroll
        for (int j = 0; j < 4; ++j) {
            const int col   = col0 + wc + j * 16 + (lane & 15);
            const int rbase = row0 + wr + i * 16 + (lane >> 4) * 4;
            #pragma unroll
            for (int r = 0; r < 4; ++r)
                Cb[(size_t)(rbase + r) * DDIM + col] = acc[i][j][r];
        }
    }
}

// ---------------------------------------------------------------------------
// masked softmax: reads raw bf16 scores (only s<len), writes normalized
// fp32 to Sout (full row) + bf16 back to P (up to roundup(len,64)).
// ---------------------------------------------------------------------------
__global__ __launch_bounds__(256) void softmax_kernel(
    __bf16* __restrict__ P, float* __restrict__ Sout,
    const int* __restrict__ len_p)
{
    const int row = blockIdx.x;          // n*TD + t
    const int n   = row >> 10;           // TD = 1024
    const int len = len_p[n];
    const int kmax = (len + 63) & ~63;
    __bf16* Pr = P    + (size_t)row * TEDIM;
    float*  Sr = Sout + (size_t)row * TEDIM;

    const int t    = threadIdx.x;
    const int lane = t & 63;
    const int w    = t >> 6;
    const int s0   = t * 8;

    float v[8];
    if (s0 < len) {
        us8 raw = *reinterpret_cast<const us8*>(&Pr[s0]);
        #pragma unroll
        for (int i = 0; i < 8; ++i) {
            v[i] = bits_f32(raw[i]);
            if (s0 + i >= len) v[i] = -INFINITY;
        }
    } else {
        #pragma unroll
        for (int i = 0; i < 8; ++i) v[i] = -INFINITY;
    }

    float mx = v[0];
    #pragma unroll
    for (int i = 1; i < 8; ++i) mx = fmaxf(mx, v[i]);
    #pragma unroll
    for (int off = 32; off; off >>= 1) mx = fmaxf(mx, __shfl_xor(mx, off));

    __shared__ float redm[4], reds[4];
    if (lane == 0) redm[w] = mx;
    __syncthreads();
    mx = fmaxf(fmaxf(redm[0], redm[1]), fmaxf(redm[2], redm[3]));

    float e[8];
    float sum = 0.f;
    #pragma unroll
    for (int i = 0; i < 8; ++i) { e[i] = __expf(v[i] - mx); sum += e[i]; }
    #pragma unroll
    for (int off = 32; off; off >>= 1) sum += __shfl_xor(sum, off);
    if (lane == 0) reds[w] = sum;
    __syncthreads();
    sum = reds[0] + reds[1] + reds[2] + reds[3];

    const float r = 1.0f / sum;
    float p[8];
    #pragma unroll
    for (int i = 0; i < 8; ++i) p[i] = e[i] * r;

    float4 oa = {p[0], p[1], p[2], p[3]};
    float4 ob = {p[4], p[5], p[6], p[7]};
    *reinterpret_cast<float4*>(&Sr[s0])     = oa;   // full row (zeros in tail)
    *reinterpret_cast<float4*>(&Sr[s0 + 4]) = ob;

    if (s0 < kmax) {                     // contexts reads only [0, kmax)
        us8 o;
        #pragma unroll
        for (int i = 0; i < 8; ++i) o[i] = bf16_bits(p[i]);
        *reinterpret_cast<us8*>(&Pr[s0]) = o;
    }
}

extern "C" void kernel_launch(void* const* d_in, const int* in_sizes, int n_in,
                              void* d_out, int out_size, void* d_ws, size_t ws_size,
                              hipStream_t stream) {
    const float* Q       = (const float*)d_in[0];
    const float* M       = (const float*)d_in[1];
    const int*   lengths = (const int*)d_in[2];

    float* ctx   = (float*)d_out;                        // [N, TD, D]
    float* align = ctx + (size_t)NB * TDIM * DDIM;       // [N, TD, TE]

    // workspace (bf16 elements)
    __bf16* Qb = (__bf16*)d_ws;                          // [N, TD, D]
    __bf16* Mb = Qb + (size_t)NB * TDIM * DDIM;          // [N, TE, D]
    __bf16* Mt = Mb + (size_t)NB * TEDIM * DDIM;         // [N, D, TE]
    __bf16* Pb = Mt + (size_t)NB * DDIM * TEDIM;         // [N, TD, TE]

    dim3 blk(256);
    // 1) Q cast + M cast/transpose (dead s-tiles skipped)
    prepass_kernel<<<dim3(32, 16, 10), blk, 0, stream>>>(Q, M, Qb, Mb, Mt, lengths);
    // 2) scores: paired col-tiles {x,15-x} per block; mask-skip
    scores_kernel<<<dim3(8, TDIM / 128, NB), blk, 0, stream>>>(Qb, Mb, Pb, lengths);
    // 3) masked softmax: Pb raw -> align (fp32) + Pb (bf16 normalized)
    softmax_kernel<<<dim3(NB * TDIM), blk, 0, stream>>>(Pb, align, lengths);
    // 4) contexts: C = Pb·Mtᵀ, K bounded by roundup(len,64); col-per-XCD
    contexts_kernel<<<dim3(DDIM / 128, TDIM / 128, NB), blk, 0, stream>>>(
        Pb, Mt, ctx, lengths);
}

// Round 9
// 261.433 us; speedup vs baseline: 1.6227x; 1.0211x over previous
//
#include <hip/hip_runtime.h>
#include <hip/hip_bf16.h>

// DotProductAttention: N=8, TD=1024, TE=2048, D=1024, fp32 in/out.
// Pipeline (mask-aware):
//   1) prepass: Q -> Qb (bf16); M -> Mb + Mt (bf16), skip s>=len
//   2) scores GEMM: 256x256 8-phase (T2+T3+T4+T5), skip col-tiles >= len
//   3) masked softmax: Praw -> align (fp32) + Pb (bf16, up to roundup(len,64))
//   4) contexts GEMM: 128x128 dbuf, K bounded by roundup(len,64)
#define NB 8
#define TDIM 1024
#define TEDIM 2048
#define DDIM 1024

typedef __bf16 bf16x8 __attribute__((ext_vector_type(8)));
typedef float f32x4 __attribute__((ext_vector_type(4)));
typedef unsigned short us8 __attribute__((ext_vector_type(8)));

static __device__ __forceinline__ void gld_lds16(const __bf16* g, __bf16* l) {
    __builtin_amdgcn_global_load_lds(
        (const __attribute__((address_space(1))) void*)g,
        (__attribute__((address_space(3))) void*)l,
        16, 0, 0);
}

static __device__ __forceinline__ unsigned short bf16_bits(float f) {
    __bf16 h = (__bf16)f;
    return __builtin_bit_cast(unsigned short, h);
}
static __device__ __forceinline__ float bits_f32(unsigned short u) {
    return (float)__builtin_bit_cast(__bf16, u);
}

// ---------------------------------------------------------------------------
// Prepass: z<8 -> M 64x64 transpose tiles (skip dead s-tiles);
//          z>=8 -> Q fp32->bf16 cast.
// ---------------------------------------------------------------------------
__global__ __launch_bounds__(256) void prepass_kernel(
    const float* __restrict__ Q, const float* __restrict__ M,
    __bf16* __restrict__ Qb, __bf16* __restrict__ Mb, __bf16* __restrict__ Mt,
    const int* __restrict__ len_p)
{
    const int z = blockIdx.z;
    const int t = threadIdx.x;

    if (z >= NB) {                       // ---- Q cast ----
        const int flat = (z - NB) * 512 + blockIdx.y * 32 + blockIdx.x;
        const size_t base = (size_t)flat * 8192 + (size_t)t * 8;
        #pragma unroll
        for (int c = 0; c < 4; ++c) {
            const size_t i = base + (size_t)c * 2048;
            float4 a = *reinterpret_cast<const float4*>(&Q[i]);
            float4 b = *reinterpret_cast<const float4*>(&Q[i + 4]);
            us8 o;
            o[0] = bf16_bits(a.x); o[1] = bf16_bits(a.y);
            o[2] = bf16_bits(a.z); o[3] = bf16_bits(a.w);
            o[4] = bf16_bits(b.x); o[5] = bf16_bits(b.y);
            o[6] = bf16_bits(b.z); o[7] = bf16_bits(b.w);
            *reinterpret_cast<us8*>(&Qb[i]) = o;
        }
        return;
    }

    // ---- M cast + transpose ----
    const int n  = z;
    const int s0 = blockIdx.x * 64;
    if (s0 >= len_p[n]) return;          // dead region: never read downstream
    const int d0 = blockIdx.y * 64;
    const float* Mn  = M  + (size_t)n * TEDIM * DDIM;
    __bf16*      Mbn = Mb + (size_t)n * TEDIM * DDIM;
    __bf16*      Mtn = Mt + (size_t)n * DDIM * TEDIM;

    __shared__ float tile[64][65];

    #pragma unroll
    for (int j = 0; j < 4; ++j) {
        const int flat = j * 256 + t;
        const int r  = flat >> 4;
        const int c4 = (flat & 15) * 4;
        float4 v = *reinterpret_cast<const float4*>(
            &Mn[(size_t)(s0 + r) * DDIM + d0 + c4]);
        tile[r][c4 + 0] = v.x; tile[r][c4 + 1] = v.y;
        tile[r][c4 + 2] = v.z; tile[r][c4 + 3] = v.w;
        ushort4 o;
        o.x = bf16_bits(v.x); o.y = bf16_bits(v.y);
        o.z = bf16_bits(v.z); o.w = bf16_bits(v.w);
        *reinterpret_cast<ushort4*>(&Mbn[(size_t)(s0 + r) * DDIM + d0 + c4]) = o;
    }
    __syncthreads();

    const int dr  = t >> 2;
    const int sc0 = (t & 3) * 16;
    us8 o0, o1;
    #pragma unroll
    for (int i = 0; i < 8; ++i)  o0[i] = bf16_bits(tile[sc0 + i][dr]);
    #pragma unroll
    for (int i = 0; i < 8; ++i)  o1[i] = bf16_bits(tile[sc0 + 8 + i][dr]);
    __bf16* dst = &Mtn[(size_t)(d0 + dr) * TEDIM + s0 + sc0];
    *reinterpret_cast<us8*>(dst)     = o0;
    *reinterpret_cast<us8*>(dst + 8) = o1;
}

// ---------------------------------------------------------------------------
// Scores GEMM: 256x256 tile, BK=64, 512 thr / 8 waves (2M x 4N), 8-phase-ish
// schedule: per K-tile 4 phases, each {ds_read quadrant | stage -> barrier ->
// lgkmcnt(0) -> setprio(1) -> 16 MFMA -> setprio(0) -> barrier}. Staging
// front-loaded (phases 0-1) so boundary vmcnt(0) has >=2 phases of cover.
// LDS 128KB dbuf; source-swizzled staging, XOR-unswizzled reads (rule #21).
// Grid: (ct=8, rt=4, n=8) = 256 blocks = 1/CU; XCD = ct (M panel L2-local).
// ---------------------------------------------------------------------------
__global__ __launch_bounds__(512) void scores256_kernel(
    const __bf16* __restrict__ Qb, const __bf16* __restrict__ Mb,
    __bf16* __restrict__ Pb, const int* __restrict__ len_p)
{
    const int n   = blockIdx.z;
    const int len = len_p[n];
    const int ct  = blockIdx.x;                  // XCD = ct
    const int col0 = ct * 256;
    if (col0 >= len) return;                     // fully masked: dead
    const int row0 = blockIdx.y * 256;

    const __bf16* Ab = Qb + (size_t)n * TDIM * DDIM + (size_t)row0 * DDIM;
    const __bf16* Bb = Mb + (size_t)n * TEDIM * DDIM + (size_t)col0 * DDIM;
    __bf16*       Cb = Pb + (size_t)n * TDIM * TEDIM;

    __shared__ __align__(16) __bf16 As[2 * 256 * 64];   // 64 KB
    __shared__ __align__(16) __bf16 Bs[2 * 256 * 64];   // 64 KB

    const int t    = threadIdx.x;
    const int lane = t & 63;
    const int w    = t >> 6;
    const int wr   = (w >> 2) * 128;     // 2 wave-rows of 128
    const int wc   = (w & 3) * 64;       // 4 wave-cols of 64

    f32x4 acc[8][4] = {};

    // stage one 256x64 operand tile chunk-group j (4 groups = whole tile)
    auto stageA = [&](int buf, int k0, int j) {
        const int slot = j * 512 + t;
        const int r    = slot >> 3;
        const int cg   = (slot & 7) ^ (r & 7);
        gld_lds16(Ab + (size_t)r * DDIM + k0 + cg * 8,
                  As + buf * 16384 + slot * 8);
    };
    auto stageB = [&](int buf, int k0, int j) {
        const int slot = j * 512 + t;
        const int r    = slot >> 3;
        const int cg   = (slot & 7) ^ (r & 7);
        gld_lds16(Bb + (size_t)r * DDIM + k0 + cg * 8,
                  Bs + buf * 16384 + slot * 8);
    };

    bf16x8 af[4][2], bf0[2][2], bf1[2][2];

    auto readA = [&](const __bf16* Ac, int mh) {
        #pragma unroll
        for (int i = 0; i < 4; ++i) {
            const int ra = wr + (mh * 4 + i) * 16 + (lane & 15);
            #pragma unroll
            for (int kk = 0; kk < 2; ++kk) {
                const int ca = (kk * 4 + (lane >> 4)) ^ (ra & 7);
                af[i][kk] = *reinterpret_cast<const bf16x8*>(&Ac[ra * 64 + ca * 8]);
            }
        }
    };
    auto readB = [&](const __bf16* Bc, int nh, bf16x8 (&b)[2][2]) {
        #pragma unroll
        for (int j = 0; j < 2; ++j) {
            const int rb = wc + (nh * 2 + j) * 16 + (lane & 15);
            #pragma unroll
            for (int kk = 0; kk < 2; ++kk) {
                const int cb = (kk * 4 + (lane >> 4)) ^ (rb & 7);
                b[j][kk] = *reinterpret_cast<const bf16x8*>(&Bc[rb * 64 + cb * 8]);
            }
        }
    };
    auto mfma_quad = [&](int mb, int nb, bf16x8 (&b)[2][2]) {
        #pragma unroll
        for (int kk = 0; kk < 2; ++kk)
            #pragma unroll
            for (int i = 0; i < 4; ++i)
                #pragma unroll
                for (int j = 0; j < 2; ++j)
                    acc[mb + i][nb + j] = __builtin_amdgcn_mfma_f32_16x16x32_bf16(
                        af[i][kk], b[j][kk], acc[mb + i][nb + j], 0, 0, 0);
    };

    // prologue: stage K-tile 0 into buf 0
    #pragma unroll
    for (int j = 0; j < 4; ++j) { stageA(0, 0, j); stageB(0, 0, j); }
    asm volatile("s_waitcnt vmcnt(0)" ::: "memory");
    __builtin_amdgcn_sched_barrier(0);
    __builtin_amdgcn_s_barrier();

    int buf = 0;
    for (int kt = 0; kt < 16; ++kt) {
        const int  k0n = (kt + 1) * 64;
        const bool pf  = (kt < 15);
        const __bf16* Ac = As + buf * 16384;
        const __bf16* Bc = Bs + buf * 16384;

        // ---- phase 0: quadrant (mh=0, nh=0); prefetch next-A (all 4) ----
        readA(Ac, 0);
        readB(Bc, 0, bf0);
        if (pf) { stageA(buf ^ 1, k0n, 0); stageA(buf ^ 1, k0n, 1);
                  stageA(buf ^ 1, k0n, 2); stageA(buf ^ 1, k0n, 3); }
        __builtin_amdgcn_s_barrier();
        asm volatile("s_waitcnt lgkmcnt(0)" ::: "memory");
        __builtin_amdgcn_sched_barrier(0);
        __builtin_amdgcn_s_setprio(1);
        mfma_quad(0, 0, bf0);
        __builtin_amdgcn_s_setprio(0);
        __builtin_amdgcn_s_barrier();

        // ---- phase 1: (mh=0, nh=1); prefetch next-B (all 4) ----
        readB(Bc, 1, bf1);
        if (pf) { stageB(buf ^ 1, k0n, 0); stageB(buf ^ 1, k0n, 1);
                  stageB(buf ^ 1, k0n, 2); stageB(buf ^ 1, k0n, 3); }
        __builtin_amdgcn_s_barrier();
        asm volatile("s_waitcnt lgkmcnt(0)" ::: "memory");
        __builtin_amdgcn_sched_barrier(0);
        __builtin_amdgcn_s_setprio(1);
        mfma_quad(0, 2, bf1);
        __builtin_amdgcn_s_setprio(0);
        __builtin_amdgcn_s_barrier();

        // ---- phase 2: (mh=1, nh=0) ----
        readA(Ac, 1);
        __builtin_amdgcn_s_barrier();
        asm volatile("s_waitcnt lgkmcnt(0)" ::: "memory");
        __builtin_amdgcn_sched_barrier(0);
        __builtin_amdgcn_s_setprio(1);
        mfma_quad(4, 0, bf0);
        __builtin_amdgcn_s_setprio(0);
        __builtin_amdgcn_s_barrier();

        // ---- phase 3: (mh=1, nh=1); boundary drain ----
        __builtin_amdgcn_s_setprio(1);
        mfma_quad(4, 2, bf1);
        __builtin_amdgcn_s_setprio(0);
        asm volatile("s_waitcnt vmcnt(0)" ::: "memory");
        __builtin_amdgcn_sched_barrier(0);
        __builtin_amdgcn_s_barrier();
        buf ^= 1;
    }

    // epilogue: scale 1/32, cvt bf16, store
    #pragma unroll
    for (int mi = 0; mi < 8; ++mi) {
        #pragma unroll
        for (int ni = 0; ni < 4; ++ni) {
            const int col   = col0 + wc + ni * 16 + (lane & 15);
            const int rbase = row0 + wr + mi * 16 + (lane >> 4) * 4;
            #pragma unroll
            for (int r = 0; r < 4; ++r)
                Cb[(size_t)(rbase + r) * TEDIM + col] =
                    (__bf16)(acc[mi][ni][r] * 0.03125f);
        }
    }
}

// ---------------------------------------------------------------------------
// 128x128 tile, BK=64, double-buffered, counted vmcnt (contexts).
// ---------------------------------------------------------------------------
template<int LDA, int LDB>
static __device__ __forceinline__ void tile_gemm_dbuf(
    const __bf16* __restrict__ Ab, const __bf16* __restrict__ Bb,
    __bf16* As, __bf16* Bs, int klim, int t, int lane, int wr, int wc,
    f32x4 (&acc)[4][4])
{
    const int nk = klim >> 6;

    auto stage = [&](int buf, int k0) {
        #pragma unroll
        for (int j = 0; j < 4; ++j) {
            const int slot = j * 256 + t;
            const int r    = slot >> 3;
            const int cg   = (slot & 7) ^ (r & 7);
            gld_lds16(Ab + (size_t)r * LDA + k0 + cg * 8,
                      As + buf * 8192 + slot * 8);
            gld_lds16(Bb + (size_t)r * LDB + k0 + cg * 8,
                      Bs + buf * 8192 + slot * 8);
        }
    };

    stage(0, 0);
    int buf = 0;
    for (int ki = 0; ki < nk; ++ki) {
        if (ki + 1 < nk) {
            stage(buf ^ 1, (ki + 1) << 6);
            asm volatile("s_waitcnt vmcnt(8)" ::: "memory");
        } else {
            asm volatile("s_waitcnt vmcnt(0)" ::: "memory");
        }
        __builtin_amdgcn_sched_barrier(0);
        __builtin_amdgcn_s_barrier();

        const __bf16* Ac = As + buf * 8192;
        const __bf16* Bc = Bs + buf * 8192;
        #pragma unroll
        for (int kk = 0; kk < 2; ++kk) {
            bf16x8 af[4], bfr[4];
            #pragma unroll
            for (int i = 0; i < 4; ++i) {
                const int rowa = wr + i * 16 + (lane & 15);
                const int ca   = (kk * 4 + (lane >> 4)) ^ (rowa & 7);
                af[i] = *reinterpret_cast<const bf16x8*>(&Ac[rowa * 64 + ca * 8]);
                const int rowb = wc + i * 16 + (lane & 15);
                const int cb   = (kk * 4 + (lane >> 4)) ^ (rowb & 7);
                bfr[i] = *reinterpret_cast<const bf16x8*>(&Bc[rowb * 64 + cb * 8]);
            }
            #pragma unroll
            for (int i = 0; i < 4; ++i)
                #pragma unroll
                for (int j = 0; j < 4; ++j)
                    acc[i][j] = __builtin_amdgcn_mfma_f32_16x16x32_bf16(
                        af[i], bfr[j], acc[i][j], 0, 0, 0);
        }
        asm volatile("s_waitcnt lgkmcnt(0)" ::: "memory");
        __builtin_amdgcn_sched_barrier(0);
        __builtin_amdgcn_s_barrier();
        buf ^= 1;
    }
}

// ---------------------------------------------------------------------------
// Contexts GEMM: C = Pb·Mtᵀ, K bounded by roundup(len,64). One D-col tile
// per XCD (blockIdx.x & 7): per-XCD work = sum_n len_n, Mt panel L2-hot.
// ---------------------------------------------------------------------------
__global__ __launch_bounds__(256) void contexts_kernel(
    const __bf16* __restrict__ Pb, const __bf16* __restrict__ Mt,
    float* __restrict__ C, const int* __restrict__ len_p)
{
    const int n    = blockIdx.z;
    const int len  = len_p[n];
    const int klim = (len + 63) & ~63;
    const int col0 = blockIdx.x * 128;               // D cols, XCD = x & 7
    const int row0 = blockIdx.y * 128;

    __shared__ __align__(16) __bf16 As[2 * 128 * 64];
    __shared__ __align__(16) __bf16 Bs[2 * 128 * 64];

    const int t    = threadIdx.x;
    const int lane = t & 63;
    const int w    = t >> 6;
    const int wr   = (w >> 1) * 64;
    const int wc   = (w & 1) * 64;

    const __bf16* Ab = Pb + (size_t)n * TDIM * TEDIM + (size_t)row0 * TEDIM;
    const __bf16* Bb = Mt + (size_t)n * DDIM * TEDIM + (size_t)col0 * TEDIM;
    float*        Cb = C  + (size_t)n * TDIM * DDIM;

    f32x4 acc[4][4] = {};
    tile_gemm_dbuf<TEDIM, TEDIM>(Ab, Bb, As, Bs, klim, t, lane, wr, wc, acc);

    #pragma unroll
    for (int i = 0; i < 4; ++i) {
        #pragma unroll
        for (int j = 0; j < 4; ++j) {
            const int col   = col0 + wc + j * 16 + (lane & 15);
            const int rbase = row0 + wr + i * 16 + (lane >> 4) * 4;
            #pragma unroll
            for (int r = 0; r < 4; ++r)
                Cb[(size_t)(rbase + r) * DDIM + col] = acc[i][j][r];
        }
    }
}

// ---------------------------------------------------------------------------
// masked softmax: reads raw bf16 scores (only s<len), writes normalized
// fp32 to Sout (full row) + bf16 back to P (up to roundup(len,64)).
// ---------------------------------------------------------------------------
__global__ __launch_bounds__(256) void softmax_kernel(
    __bf16* __restrict__ P, float* __restrict__ Sout,
    const int* __restrict__ len_p)
{
    const int row = blockIdx.x;          // n*TD + t
    const int n   = row >> 10;           // TD = 1024
    const int len = len_p[n];
    const int kmax = (len + 63) & ~63;
    __bf16* Pr = P    + (size_t)row * TEDIM;
    float*  Sr = Sout + (size_t)row * TEDIM;

    const int t    = threadIdx.x;
    const int lane = t & 63;
    const int w    = t >> 6;
    const int s0   = t * 8;

    float v[8];
    if (s0 < len) {
        us8 raw = *reinterpret_cast<const us8*>(&Pr[s0]);
        #pragma unroll
        for (int i = 0; i < 8; ++i) {
            v[i] = bits_f32(raw[i]);
            if (s0 + i >= len) v[i] = -INFINITY;
        }
    } else {
        #pragma unroll
        for (int i = 0; i < 8; ++i) v[i] = -INFINITY;
    }

    float mx = v[0];
    #pragma unroll
    for (int i = 1; i < 8; ++i) mx = fmaxf(mx, v[i]);
    #pragma unroll
    for (int off = 32; off; off >>= 1) mx = fmaxf(mx, __shfl_xor(mx, off));

    __shared__ float redm[4], reds[4];
    if (lane == 0) redm[w] = mx;
    __syncthreads();
    mx = fmaxf(fmaxf(redm[0], redm[1]), fmaxf(redm[2], redm[3]));

    float e[8];
    float sum = 0.f;
    #pragma unroll
    for (int i = 0; i < 8; ++i) { e[i] = __expf(v[i] - mx); sum += e[i]; }
    #pragma unroll
    for (int off = 32; off; off >>= 1) sum += __shfl_xor(sum, off);
    if (lane == 0) reds[w] = sum;
    __syncthreads();
    sum = reds[0] + reds[1] + reds[2] + reds[3];

    const float r = 1.0f / sum;
    float p[8];
    #pragma unroll
    for (int i = 0; i < 8; ++i) p[i] = e[i] * r;

    float4 oa = {p[0], p[1], p[2], p[3]};
    float4 ob = {p[4], p[5], p[6], p[7]};
    *reinterpret_cast<float4*>(&Sr[s0])     = oa;   // full row (zeros in tail)
    *reinterpret_cast<float4*>(&Sr[s0 + 4]) = ob;

    if (s0 < kmax) {                     // contexts reads only [0, kmax)
        us8 o;
        #pragma unroll
        for (int i = 0; i < 8; ++i) o[i] = bf16_bits(p[i]);
        *reinterpret_cast<us8*>(&Pr[s0]) = o;
    }
}

extern "C" void kernel_launch(void* const* d_in, const int* in_sizes, int n_in,
                              void* d_out, int out_size, void* d_ws, size_t ws_size,
                              hipStream_t stream) {
    const float* Q       = (const float*)d_in[0];
    const float* M       = (const float*)d_in[1];
    const int*   lengths = (const int*)d_in[2];

    float* ctx   = (float*)d_out;                        // [N, TD, D]
    float* align = ctx + (size_t)NB * TDIM * DDIM;       // [N, TD, TE]

    // workspace (bf16 elements)
    __bf16* Qb = (__bf16*)d_ws;                          // [N, TD, D]
    __bf16* Mb = Qb + (size_t)NB * TDIM * DDIM;          // [N, TE, D]
    __bf16* Mt = Mb + (size_t)NB * TEDIM * DDIM;         // [N, D, TE]
    __bf16* Pb = Mt + (size_t)NB * DDIM * TEDIM;         // [N, TD, TE]

    // 1) Q cast + M cast/transpose (dead s-tiles skipped)
    prepass_kernel<<<dim3(32, 16, 10), dim3(256), 0, stream>>>(
        Q, M, Qb, Mb, Mt, lengths);
    // 2) scores: 256^2 8-phase; grid (ct, rt, n) = 1 block/CU; mask-skip
    scores256_kernel<<<dim3(TEDIM / 256, TDIM / 256, NB), dim3(512), 0, stream>>>(
        Qb, Mb, Pb, lengths);
    // 3) masked softmax: Pb raw -> align (fp32) + Pb (bf16 normalized)
    softmax_kernel<<<dim3(NB * TDIM), dim3(256), 0, stream>>>(Pb, align, lengths);
    // 4) contexts: C = Pb·Mtᵀ, K bounded by roundup(len,64); col-per-XCD
    contexts_kernel<<<dim3(DDIM / 128, TDIM / 128, NB), dim3(256), 0, stream>>>(
        Pb, Mt, ctx, lengths);
}